// Round 14
// baseline (382.939 us; speedup 1.0000x reference)
//
#include <hip/hip_runtime.h>
#include <hip/hip_bf16.h>
#include <math.h>

// CHRONOS inference. Round 14: R13 (380.8us best) with ONE isolated change:
// mgemm3 BK=64 — halves the 2-barrier K-loop's vmcnt drains (64->32 iters,
// 8 MFMA per barrier pair). R12 bundled this with a bad fusion; now isolated.

#define HID 256
#define HEADS 8
#define FIN 235

typedef __attribute__((ext_vector_type(8))) short short8;
typedef __attribute__((ext_vector_type(4))) float floatx4;

__device__ __forceinline__ float elu_f(float x) { return x > 0.f ? x : __expf(x) - 1.f; }
__device__ __forceinline__ float bf2f(unsigned short u) {
  return __uint_as_float(((unsigned int)u) << 16);
}
__device__ __forceinline__ unsigned short f2bfu(float f) {
  union { __hip_bfloat16 b; unsigned short u; } c;
  c.b = __float2bfloat16(f);
  return c.u;
}

// ---------------- xcvt + edge count + logit init (partitioned grid) ----------------
__global__ void xc_k(const float* __restrict__ x, __hip_bfloat16* __restrict__ xb,
                     const int* __restrict__ ei, int* __restrict__ deg,
                     const float* __restrict__ b2, float* __restrict__ out,
                     int M, int E, int xblocks, int cblocks) {
  int b = blockIdx.x;
  if (b < xblocks) {
    int id = b * 256 + threadIdx.x;
    if (id >= M * 256) return;
    int m = id >> 8, k = id & 255;
    xb[id] = (k < FIN) ? __float2bfloat16(x[(size_t)m * FIN + k]) : __float2bfloat16(0.f);
  } else if (b < xblocks + cblocks) {
    int i = (b - xblocks) * 256 + threadIdx.x;
    if (i < E) atomicAdd(&deg[ei[E + i]], 1);
  } else {
    int i = (b - xblocks - cblocks) * 256 + threadIdx.x;
    if (i < M * 2) out[i] = b2[i & 1];
  }
}

// batched weight transpose+cast (+ aproj at z=14)
__global__ void wprep_k(const float* __restrict__ w_in, const float* __restrict__ w_t1,
                        const float* __restrict__ w_g1, const float* __restrict__ w_t2,
                        const float* __restrict__ w_g2, const float* __restrict__ w_c1,
                        const float* __restrict__ w_g3, const float* __restrict__ a_s3,
                        const float* __restrict__ a_d3, __hip_bfloat16* __restrict__ wtin,
                        __hip_bfloat16* __restrict__ wtpair, __hip_bfloat16* __restrict__ wtt2,
                        __hip_bfloat16* __restrict__ wtg2, __hip_bfloat16* __restrict__ wtc1,
                        __hip_bfloat16* __restrict__ wtg3s, float* __restrict__ apj) {
  __shared__ float t[32][33];
  int z = blockIdx.z;
  if (z == 14) {
    int idx = (blockIdx.y * 8 + blockIdx.x) * 256 + threadIdx.y * 32 + threadIdx.x;
    if (idx < 256 * 16) {
      int k = idx >> 4, o = idx & 15;
      int h = o >> 1;
      const float* av = (o & 1) ? (a_d3 + h * 256) : (a_s3 + h * 256);
      const float* wr = w_g3 + (size_t)k * 2048 + h * 256;
      float s = 0.f;
      for (int c = 0; c < 256; c++) s += wr[c] * av[c];
      apj[idx] = s;
    }
    return;
  }
  const float* src;
  __hip_bfloat16* dst;
  int K, Kpad, Nstride;
  if (z == 5) {
    src = w_c1; dst = wtc1; K = 512; Kpad = 512; Nstride = 256;
  } else {
    if (blockIdx.y >= 8) return;
    switch (z) {
      case 0: src = w_in; dst = wtin; K = FIN; Kpad = 256; Nstride = 256; break;
      case 1: src = w_t1; dst = wtpair; K = 256; Kpad = 256; Nstride = 256; break;
      case 2: src = w_g1; dst = wtpair + 256 * 256; K = 256; Kpad = 256; Nstride = 256; break;
      case 3: src = w_t2; dst = wtt2; K = 256; Kpad = 256; Nstride = 256; break;
      case 4: src = w_g2; dst = wtg2; K = 256; Kpad = 256; Nstride = 256; break;
      default: {
        int h = z - 6;
        src = w_g3 + h * 256; dst = wtg3s + h * 256; K = 256; Kpad = 2048; Nstride = 2048;
      }
    }
  }
  int nb = blockIdx.x * 32, kb = blockIdx.y * 32;
  int tx = threadIdx.x, ty = threadIdx.y;
#pragma unroll
  for (int j = 0; j < 32; j += 8) {
    int k = kb + ty + j;
    t[ty + j][tx] = (k < K) ? src[(size_t)k * Nstride + nb + tx] : 0.f;
  }
  __syncthreads();
#pragma unroll
  for (int j = 0; j < 32; j += 8) {
    int n = nb + ty + j;
    int k = kb + tx;
    dst[(size_t)n * Kpad + k] = __float2bfloat16(t[tx][ty + j]);
  }
}

// ---------------- CSR build ----------------
__global__ void scan_k(const int* __restrict__ deg, int* __restrict__ rp, int n) {
  __shared__ int wsum[16];
  __shared__ int s_carry;
  int tid = threadIdx.x, lane = tid & 63, wid = tid >> 6;
  if (tid == 0) { s_carry = 0; rp[0] = 0; }
  __syncthreads();
  for (int base = 0; base < n; base += 1024) {
    int i = base + tid;
    int x = (i < n) ? (deg[i] + 1) : 0;  // +1 self-loop
#pragma unroll
    for (int off = 1; off < 64; off <<= 1) {
      int y = __shfl_up(x, off);
      if (lane >= off) x += y;
    }
    if (lane == 63) wsum[wid] = x;
    __syncthreads();
    if (wid == 0 && lane < 16) {
      int s = wsum[lane];
#pragma unroll
      for (int off = 1; off < 16; off <<= 1) {
        int y = __shfl_up(s, off);
        if (lane >= off) s += y;
      }
      wsum[lane] = s;
    }
    __syncthreads();
    int offset = s_carry + (wid > 0 ? wsum[wid - 1] : 0);
    if (i < n) rp[i + 1] = offset + x;
    __syncthreads();
    if (tid == 1023) s_carry += wsum[15];
    __syncthreads();
  }
}

__global__ void fill_k(const int* __restrict__ ei, const int* __restrict__ rp,
                       int* __restrict__ fillc, int* __restrict__ colA, int E, int n) {
  int i = blockIdx.x * blockDim.x + threadIdx.x;
  if (i < E) {
    int d = ei[E + i];
    int pos = rp[d] + atomicAdd(&fillc[d], 1);
    colA[pos] = ei[i];
  } else if (i < E + n) {
    int v = i - E;
    int pos = rp[v] + atomicAdd(&fillc[v], 1);
    colA[pos] = v;
  }
}

// ---------------- bf16 MFMA GEMM, TILE 64x64, BK=32 ----------------
// ALPHA: also emit layer-2 attention logits from acc (head = 2*bx + wc).
template <int ACT, int ALPHA>
__global__ __launch_bounds__(256) void mgemm64_k(
    const __hip_bfloat16* __restrict__ A, const __hip_bfloat16* __restrict__ Bt,
    const float* __restrict__ bias, __hip_bfloat16* __restrict__ Cb,
    int ldc, int M, int N, int K, const float* __restrict__ a_s,
    const float* __restrict__ a_d, float* __restrict__ as_, float* __restrict__ ad_) {
  __shared__ short As[64 * 40];
  __shared__ short Bs[64 * 40];
  int tid = threadIdx.x;
  int row0 = blockIdx.y * 64, col0 = blockIdx.x * 64;
  int w = tid >> 6, lane = tid & 63;
  int wr = w >> 1, wc = w & 1;
  int quad = lane >> 4, l16 = lane & 15;
  floatx4 zero = {0.f, 0.f, 0.f, 0.f};
  floatx4 acc[2][2];
#pragma unroll
  for (int i = 0; i < 2; i++)
#pragma unroll
    for (int j = 0; j < 2; j++) acc[i][j] = zero;

  int srow = tid >> 2, sq = tid & 3;
  const __hip_bfloat16* Ap = A + (size_t)(row0 + srow) * K + sq * 8;
  const __hip_bfloat16* Bp = Bt + (size_t)(col0 + srow) * K + sq * 8;
  bool aok = (row0 + srow) < M;

  uint4 a1 = make_uint4(0, 0, 0, 0);
  if (aok) a1 = *(const uint4*)(Ap);
  uint4 b1 = *(const uint4*)(Bp);

  for (int k0 = 0; k0 < K; k0 += 32) {
    __syncthreads();
    *(uint4*)&As[srow * 40 + sq * 8] = a1;
    *(uint4*)&Bs[srow * 40 + sq * 8] = b1;
    int kn = k0 + 32;
    if (kn < K) {
      if (aok) a1 = *(const uint4*)(Ap + kn);
      b1 = *(const uint4*)(Bp + kn);
    }
    __syncthreads();
    short8 fa[2], fb[2];
#pragma unroll
    for (int i = 0; i < 2; i++) {
      fa[i] = *(const short8*)&As[(wr * 32 + i * 16 + l16) * 40 + quad * 8];
      fb[i] = *(const short8*)&Bs[(wc * 32 + i * 16 + l16) * 40 + quad * 8];
    }
#pragma unroll
    for (int mi = 0; mi < 2; mi++)
#pragma unroll
      for (int ni = 0; ni < 2; ni++)
        acc[mi][ni] = __builtin_amdgcn_mfma_f32_16x16x32_bf16(fa[mi], fb[ni], acc[mi][ni], 0, 0, 0);
  }

#pragma unroll
  for (int mi = 0; mi < 2; mi++) {
    int rbase = row0 + wr * 32 + mi * 16 + quad * 4;
#pragma unroll
    for (int ni = 0; ni < 2; ni++) {
      int c = col0 + wc * 32 + ni * 16 + l16;
      float bv = bias ? bias[c] : 0.f;
#pragma unroll
      for (int reg = 0; reg < 4; reg++) {
        int rr = rbase + reg;
        if (rr >= M) continue;
        float v = acc[mi][ni][reg] + bv;
        if (ACT == 1) v = fmaxf(v, 0.f);
        if (ACT == 2) v = elu_f(v);
        Cb[(size_t)rr * ldc + c] = __float2bfloat16(v);
      }
    }
  }

  if (ALPHA) {
    int h = 2 * blockIdx.x + wc;
    float aS0 = a_s[h * 32 + l16], aS1 = a_s[h * 32 + 16 + l16];
    float aD0 = a_d[h * 32 + l16], aD1 = a_d[h * 32 + 16 + l16];
#pragma unroll
    for (int mi = 0; mi < 2; mi++)
#pragma unroll
      for (int reg = 0; reg < 4; reg++) {
        float pS = acc[mi][0][reg] * aS0 + acc[mi][1][reg] * aS1;
        float pD = acc[mi][0][reg] * aD0 + acc[mi][1][reg] * aD1;
#pragma unroll
        for (int off = 1; off < 16; off <<= 1) {
          pS += __shfl_xor(pS, off);
          pD += __shfl_xor(pD, off);
        }
        if (l16 == 0) {
          int r = row0 + wr * 32 + mi * 16 + quad * 4 + reg;
          if (r < M) {
            as_[r * 8 + h] = pS;
            ad_[r * 8 + h] = pD;
          }
        }
      }
  }
}

// ---------------- dual GEMM (N=512): A@[w_t1 | w_g1], split epilogue ----------------
__global__ __launch_bounds__(256) void mgemm_dual_k(
    const __hip_bfloat16* __restrict__ A, const __hip_bfloat16* __restrict__ Bt,
    const float* __restrict__ bias1, __hip_bfloat16* __restrict__ O1,
    __hip_bfloat16* __restrict__ O2, int M, const float* __restrict__ a_s1,
    const float* __restrict__ a_d1, float* __restrict__ as_, float* __restrict__ ad_) {
  const int K = 256;
  __shared__ short As[64 * 40];
  __shared__ short Bs[128 * 40];
  int tid = threadIdx.x;
  int row0 = blockIdx.y * 64, col0 = blockIdx.x * 128;
  int w = tid >> 6, lane = tid & 63;
  int wr = w >> 1, wc = w & 1;
  int quad = lane >> 4, l16 = lane & 15;
  floatx4 zero = {0.f, 0.f, 0.f, 0.f};
  floatx4 acc[2][4];
#pragma unroll
  for (int i = 0; i < 2; i++)
#pragma unroll
    for (int j = 0; j < 4; j++) acc[i][j] = zero;

  int srow = tid >> 2, sq = tid & 3;
  const __hip_bfloat16* Ap = A + (size_t)(row0 + srow) * K + sq * 8;
  const __hip_bfloat16* Bp1 = Bt + (size_t)(col0 + srow) * K + sq * 8;
  const __hip_bfloat16* Bp2 = Bt + (size_t)(col0 + 64 + srow) * K + sq * 8;
  bool aok = (row0 + srow) < M;

  uint4 a1 = make_uint4(0, 0, 0, 0);
  if (aok) a1 = *(const uint4*)(Ap);
  uint4 b1 = *(const uint4*)(Bp1);
  uint4 b2 = *(const uint4*)(Bp2);

  for (int k0 = 0; k0 < K; k0 += 32) {
    __syncthreads();
    *(uint4*)&As[srow * 40 + sq * 8] = a1;
    *(uint4*)&Bs[srow * 40 + sq * 8] = b1;
    *(uint4*)&Bs[(64 + srow) * 40 + sq * 8] = b2;
    int kn = k0 + 32;
    if (kn < K) {
      if (aok) a1 = *(const uint4*)(Ap + kn);
      b1 = *(const uint4*)(Bp1 + kn);
      b2 = *(const uint4*)(Bp2 + kn);
    }
    __syncthreads();
    short8 fa[2], fb[4];
#pragma unroll
    for (int i = 0; i < 2; i++)
      fa[i] = *(const short8*)&As[(wr * 32 + i * 16 + l16) * 40 + quad * 8];
#pragma unroll
    for (int i = 0; i < 4; i++)
      fb[i] = *(const short8*)&Bs[(wc * 64 + i * 16 + l16) * 40 + quad * 8];
#pragma unroll
    for (int mi = 0; mi < 2; mi++)
#pragma unroll
      for (int ni = 0; ni < 4; ni++)
        acc[mi][ni] = __builtin_amdgcn_mfma_f32_16x16x32_bf16(fa[mi], fb[ni], acc[mi][ni], 0, 0, 0);
  }

#pragma unroll
  for (int mi = 0; mi < 2; mi++) {
    int rbase = row0 + wr * 32 + mi * 16 + quad * 4;
#pragma unroll
    for (int ni = 0; ni < 4; ni++) {
      int c = col0 + wc * 64 + ni * 16 + l16;
      bool first = c < 256;
      float bv = first ? bias1[c] : 0.f;
      int cc = first ? c : (c - 256);
#pragma unroll
      for (int reg = 0; reg < 4; reg++) {
        int rr = rbase + reg;
        if (rr >= M) continue;
        float v = acc[mi][ni][reg] + bv;
        if (first) v = fmaxf(v, 0.f);
        __hip_bfloat16* dst = first ? O1 : O2;
        dst[(size_t)rr * 256 + cc] = __float2bfloat16(v);
      }
    }
  }

  if (blockIdx.x >= 2) {
    int hb = (blockIdx.x - 2) * 4 + wc * 2;
    float aSA0 = a_s1[hb * 32 + l16], aSA1 = a_s1[hb * 32 + 16 + l16];
    float aDA0 = a_d1[hb * 32 + l16], aDA1 = a_d1[hb * 32 + 16 + l16];
    float aSB0 = a_s1[(hb + 1) * 32 + l16], aSB1 = a_s1[(hb + 1) * 32 + 16 + l16];
    float aDB0 = a_d1[(hb + 1) * 32 + l16], aDB1 = a_d1[(hb + 1) * 32 + 16 + l16];
#pragma unroll
    for (int mi = 0; mi < 2; mi++)
#pragma unroll
      for (int reg = 0; reg < 4; reg++) {
        float pSA = acc[mi][0][reg] * aSA0 + acc[mi][1][reg] * aSA1;
        float pDA = acc[mi][0][reg] * aDA0 + acc[mi][1][reg] * aDA1;
        float pSB = acc[mi][2][reg] * aSB0 + acc[mi][3][reg] * aSB1;
        float pDB = acc[mi][2][reg] * aDB0 + acc[mi][3][reg] * aDB1;
#pragma unroll
        for (int off = 1; off < 16; off <<= 1) {
          pSA += __shfl_xor(pSA, off);
          pDA += __shfl_xor(pDA, off);
          pSB += __shfl_xor(pSB, off);
          pDB += __shfl_xor(pDB, off);
        }
        if (l16 == 0) {
          int r = row0 + wr * 32 + mi * 16 + quad * 4 + reg;
          if (r < M) {
            as_[r * 8 + hb] = pSA;
            ad_[r * 8 + hb] = pDA;
            as_[r * 8 + hb + 1] = pSB;
            ad_[r * 8 + hb + 1] = pDB;
          }
        }
      }
  }
}

// ---------------- GAT3 GEMM: 64x64 tile, BK=64 (half the barrier drains), XCD swizzle ----
__global__ __launch_bounds__(256) void mgemm3_k(
    const __hip_bfloat16* __restrict__ A, const __hip_bfloat16* __restrict__ Bt,
    const float* __restrict__ bias, __hip_bfloat16* __restrict__ comb, int M) {
  const int K = 2048;
  __shared__ short As[64 * 72];
  __shared__ short Bs[64 * 72];
  int tid = threadIdx.x;
  int mg = (M + 63) >> 6;
  int total = mg * 4;
  int F = blockIdx.y * 4 + blockIdx.x;
  int Fmain = (total >> 5) << 5;
  int bx, by;
  if (F < Fmain) {
    by = (F >> 5) * 8 + (F & 7);
    bx = (F >> 3) & 3;
  } else {
    by = ((total >> 5) << 3) + ((F - Fmain) >> 2);
    bx = (F - Fmain) & 3;
  }
  int row0 = by * 64, col0 = bx * 64;
  int w = tid >> 6, lane = tid & 63;
  int wr = w >> 1, wc = w & 1;
  int quad = lane >> 4, l16 = lane & 15;
  floatx4 zero = {0.f, 0.f, 0.f, 0.f};
  floatx4 acc[2][2], sum[2][2];
#pragma unroll
  for (int i = 0; i < 2; i++)
#pragma unroll
    for (int j = 0; j < 2; j++) { acc[i][j] = zero; sum[i][j] = zero; }

  int srow = tid >> 2, sq = (tid & 3) * 8;  // k-offset in shorts (0,8,16,24)
  const __hip_bfloat16* Ap = A + (size_t)(row0 + srow) * K + sq;
  const __hip_bfloat16* Bp = Bt + (size_t)(col0 + srow) * K + sq;
  bool aok = (row0 + srow) < M;

  uint4 a1 = make_uint4(0, 0, 0, 0), a2 = make_uint4(0, 0, 0, 0);
  if (aok) { a1 = *(const uint4*)(Ap); a2 = *(const uint4*)(Ap + 32); }
  uint4 b1 = *(const uint4*)(Bp);
  uint4 b2 = *(const uint4*)(Bp + 32);

  for (int k0 = 0; k0 < K; k0 += 64) {
    __syncthreads();
    *(uint4*)&As[srow * 72 + sq] = a1;
    *(uint4*)&As[srow * 72 + sq + 32] = a2;
    *(uint4*)&Bs[srow * 72 + sq] = b1;
    *(uint4*)&Bs[srow * 72 + sq + 32] = b2;
    int kn = k0 + 64;
    if (kn < K) {
      if (aok) { a1 = *(const uint4*)(Ap + kn); a2 = *(const uint4*)(Ap + kn + 32); }
      b1 = *(const uint4*)(Bp + kn);
      b2 = *(const uint4*)(Bp + kn + 32);
    }
    __syncthreads();
#pragma unroll
    for (int c32 = 0; c32 < 2; c32++) {
      short8 fa[2], fb[2];
#pragma unroll
      for (int i = 0; i < 2; i++) {
        fa[i] = *(const short8*)&As[(wr * 32 + i * 16 + l16) * 72 + c32 * 32 + quad * 8];
        fb[i] = *(const short8*)&Bs[(wc * 32 + i * 16 + l16) * 72 + c32 * 32 + quad * 8];
      }
#pragma unroll
      for (int mi = 0; mi < 2; mi++)
#pragma unroll
        for (int ni = 0; ni < 2; ni++)
          acc[mi][ni] = __builtin_amdgcn_mfma_f32_16x16x32_bf16(fa[mi], fb[ni], acc[mi][ni], 0, 0, 0);
    }
    if (((k0 + 64) & 255) == 0) {  // head boundary: fold elu(acc + b_h)
      int h = k0 >> 8;
#pragma unroll
      for (int mi = 0; mi < 2; mi++)
#pragma unroll
        for (int ni = 0; ni < 2; ni++) {
          int c = col0 + wc * 32 + ni * 16 + l16;
          float bv = bias[h * 256 + c];
#pragma unroll
          for (int reg = 0; reg < 4; reg++) {
            sum[mi][ni][reg] += elu_f(acc[mi][ni][reg] + bv);
            acc[mi][ni][reg] = 0.f;
          }
        }
    }
  }

#pragma unroll
  for (int mi = 0; mi < 2; mi++) {
    int rbase = row0 + wr * 32 + mi * 16 + quad * 4;
#pragma unroll
    for (int ni = 0; ni < 2; ni++) {
      int c = col0 + wc * 32 + ni * 16 + l16;
#pragma unroll
      for (int reg = 0; reg < 4; reg++) {
        int rr = rbase + reg;
        if (rr >= M) continue;
        comb[(size_t)rr * 512 + c] = __float2bfloat16(sum[mi][ni][reg] * 0.125f);
      }
    }
  }
}

// ---------------- classifier: split-N=2, 64x128 tile, atomic logits ----------------
__global__ __launch_bounds__(256) void mgemm_cls_k(
    const __hip_bfloat16* __restrict__ A, const __hip_bfloat16* __restrict__ Bt,
    const float* __restrict__ bias, const float* __restrict__ w2,
    float* __restrict__ out, int M) {
  const int K = 512;
  __shared__ short As[64 * 40];
  __shared__ short Bs[128 * 40];
  __shared__ float ls[64][2][2];
  int tid = threadIdx.x;
  int row0 = blockIdx.y * 64, col0 = blockIdx.x * 128;
  int w = tid >> 6, lane = tid & 63;
  int wr = w >> 1, wc = w & 1;
  int quad = lane >> 4, l16 = lane & 15;
  floatx4 zero = {0.f, 0.f, 0.f, 0.f};
  floatx4 acc[2][4];
#pragma unroll
  for (int i = 0; i < 2; i++)
#pragma unroll
    for (int j = 0; j < 4; j++) acc[i][j] = zero;

  int srow = tid >> 2, sq = tid & 3;
  const __hip_bfloat16* Ap = A + (size_t)(row0 + srow) * K + sq * 8;
  const __hip_bfloat16* Bp1 = Bt + (size_t)(col0 + srow) * K + sq * 8;
  const __hip_bfloat16* Bp2 = Bt + (size_t)(col0 + 64 + srow) * K + sq * 8;
  bool aok = (row0 + srow) < M;

  uint4 a1 = make_uint4(0, 0, 0, 0);
  if (aok) a1 = *(const uint4*)(Ap);
  uint4 b1 = *(const uint4*)(Bp1);
  uint4 b2 = *(const uint4*)(Bp2);

  for (int k0 = 0; k0 < K; k0 += 32) {
    __syncthreads();
    *(uint4*)&As[srow * 40 + sq * 8] = a1;
    *(uint4*)&Bs[srow * 40 + sq * 8] = b1;
    *(uint4*)&Bs[(64 + srow) * 40 + sq * 8] = b2;
    int kn = k0 + 32;
    if (kn < K) {
      if (aok) a1 = *(const uint4*)(Ap + kn);
      b1 = *(const uint4*)(Bp1 + kn);
      b2 = *(const uint4*)(Bp2 + kn);
    }
    __syncthreads();
    short8 fa[2], fb[4];
#pragma unroll
    for (int i = 0; i < 2; i++)
      fa[i] = *(const short8*)&As[(wr * 32 + i * 16 + l16) * 40 + quad * 8];
#pragma unroll
    for (int i = 0; i < 4; i++)
      fb[i] = *(const short8*)&Bs[(wc * 64 + i * 16 + l16) * 40 + quad * 8];
#pragma unroll
    for (int mi = 0; mi < 2; mi++)
#pragma unroll
      for (int ni = 0; ni < 4; ni++)
        acc[mi][ni] = __builtin_amdgcn_mfma_f32_16x16x32_bf16(fa[mi], fb[ni], acc[mi][ni], 0, 0, 0);
  }

  float p0[2][4], p1[2][4];
#pragma unroll
  for (int mi = 0; mi < 2; mi++)
#pragma unroll
    for (int reg = 0; reg < 4; reg++) { p0[mi][reg] = 0.f; p1[mi][reg] = 0.f; }
#pragma unroll
  for (int mi = 0; mi < 2; mi++)
#pragma unroll
    for (int ni = 0; ni < 4; ni++) {
      int c = col0 + wc * 64 + ni * 16 + l16;
      float bv = bias[c];
      float w20 = w2[c * 2 + 0], w21 = w2[c * 2 + 1];
#pragma unroll
      for (int reg = 0; reg < 4; reg++) {
        float v = fmaxf(acc[mi][ni][reg] + bv, 0.f);
        p0[mi][reg] += v * w20;
        p1[mi][reg] += v * w21;
      }
    }
#pragma unroll
  for (int off = 1; off < 16; off <<= 1)
#pragma unroll
    for (int mi = 0; mi < 2; mi++)
#pragma unroll
      for (int reg = 0; reg < 4; reg++) {
        p0[mi][reg] += __shfl_xor(p0[mi][reg], off);
        p1[mi][reg] += __shfl_xor(p1[mi][reg], off);
      }
  if (l16 == 0) {
#pragma unroll
    for (int mi = 0; mi < 2; mi++)
#pragma unroll
      for (int reg = 0; reg < 4; reg++) {
        int rl = wr * 32 + mi * 16 + quad * 4 + reg;
        ls[rl][wc][0] = p0[mi][reg];
        ls[rl][wc][1] = p1[mi][reg];
      }
  }
  __syncthreads();
  if (tid < 64) {
    int r = row0 + tid;
    if (r < M) {
      atomicAdd(&out[r * 2 + 0], ls[tid][0][0] + ls[tid][1][0]);
      atomicAdd(&out[r * 2 + 1], ls[tid][0][1] + ls[tid][1][1]);
    }
  }
}

// ---------------- alpha3: apj in LDS, vectorized row loads ----------------
__global__ __launch_bounds__(256) void alpha3_k(const __hip_bfloat16* __restrict__ g2,
                                                const float* __restrict__ apj,
                                                float* __restrict__ as_, float* __restrict__ ad_,
                                                int M) {
  __shared__ float sapj[4096];
  int tid = threadIdx.x;
  for (int i = tid; i < 4096; i += 256) sapj[i] = apj[i];
  __syncthreads();
  int nl = tid >> 4, o = tid & 15;
  int n = blockIdx.x * 16 + nl;
  if (n >= M) return;
  const __hip_bfloat16* row = g2 + (size_t)n * 256;
  float s = 0.f;
  for (int cc = 0; cc < 256; cc += 8) {
    short8 v8 = *(const short8*)(row + cc);
#pragma unroll
    for (int j = 0; j < 8; j++)
      s += bf2f((unsigned short)v8[j]) * sapj[(cc + j) * 16 + o];
  }
  if (o & 1) ad_[n * 8 + (o >> 1)] = s;
  else as_[n * 8 + (o >> 1)] = s;
}

// ---------------- fused online-softmax aggregate (GAT1/2), wave per dst ----------------
__global__ __launch_bounds__(256) void aggf_k(const int* __restrict__ rp,
                                              const int* __restrict__ col,
                                              const __hip_bfloat16* __restrict__ hW,
                                              const float* __restrict__ as_,
                                              const float* __restrict__ ad_,
                                              const float* __restrict__ bias,
                                              __hip_bfloat16* __restrict__ out, int M) {
  int dst = blockIdx.x * 4 + (threadIdx.x >> 6);
  if (dst >= M) return;
  int t = threadIdx.x & 63;
  int h = t >> 3, c = t << 2;
  int beg = rp[dst], end = rp[dst + 1];
  float adv = ad_[dst * 8 + h];
  float m = -3.4e38f, den = 0.f;
  float a0 = 0.f, a1 = 0.f, a2 = 0.f, a3 = 0.f;
  int sN = (beg < end) ? col[beg] : 0;
  for (int i = beg; i < end; i++) {
    int s = sN;
    if (i + 1 < end) sN = col[i + 1];
    float e = as_[s * 8 + h] + adv;
    e = e > 0.f ? e : 0.2f * e;
    float mn = fmaxf(m, e);
    float sc = __expf(m - mn);
    float wgt = __expf(e - mn);
    m = mn;
    union { uint2 u; unsigned short us[4]; } uu;
    uu.u = *(const uint2*)(hW + (size_t)s * HID + c);
    den = den * sc + wgt;
    a0 = a0 * sc + wgt * bf2f(uu.us[0]);
    a1 = a1 * sc + wgt * bf2f(uu.us[1]);
    a2 = a2 * sc + wgt * bf2f(uu.us[2]);
    a3 = a3 * sc + wgt * bf2f(uu.us[3]);
  }
  float inv = 1.f / (den + 1e-16f);
  out[(size_t)dst * HID + c + 0] = __float2bfloat16(elu_f(a0 * inv + bias[c + 0]));
  out[(size_t)dst * HID + c + 1] = __float2bfloat16(elu_f(a1 * inv + bias[c + 1]));
  out[(size_t)dst * HID + c + 2] = __float2bfloat16(elu_f(a2 * inv + bias[c + 2]));
  out[(size_t)dst * HID + c + 3] = __float2bfloat16(elu_f(a3 * inv + bias[c + 3]));
}

// ---------------- edge softmax (GAT3) ----------------
__global__ __launch_bounds__(256) void esoft_k(const int* __restrict__ rp,
                                               const int* __restrict__ col,
                                               const float* __restrict__ as_,
                                               const float* __restrict__ ad_,
                                               float* __restrict__ ex,
                                               float* __restrict__ invden, int M) {
  int dst = blockIdx.x * 4 + (threadIdx.x >> 6);
  if (dst >= M) return;
  int lane = threadIdx.x & 63;
  int es = lane >> 3, h = lane & 7;
  int beg = rp[dst], end = rp[dst + 1];
  float adv = ad_[dst * 8 + h];
  float m = -3.4e38f;
  for (int i = beg + es; i < end; i += 8) {
    float e = as_[col[i] * 8 + h] + adv;
    e = e > 0.f ? e : 0.2f * e;
    m = fmaxf(m, e);
  }
  m = fmaxf(m, __shfl_xor(m, 8));
  m = fmaxf(m, __shfl_xor(m, 16));
  m = fmaxf(m, __shfl_xor(m, 32));
  float den = 0.f;
  for (int i = beg + es; i < end; i += 8) {
    float e = as_[col[i] * 8 + h] + adv;
    e = e > 0.f ? e : 0.2f * e;
    float v = __expf(e - m);
    ex[(size_t)i * 8 + h] = v;
    den += v;
  }
  den += __shfl_xor(den, 8);
  den += __shfl_xor(den, 16);
  den += __shfl_xor(den, 32);
  if (es == 0) invden[dst * 8 + h] = 1.f / (den + 1e-16f);
}

// ---------------- GAT3 aggregate: 4 dsts/block, 64 thr/dst, uint2 ----------------
__global__ __launch_bounds__(256) void agg3_k(const int* __restrict__ rp,
                                              const int* __restrict__ col,
                                              const __hip_bfloat16* __restrict__ g2,
                                              const float* __restrict__ ex,
                                              const float* __restrict__ invden,
                                              __hip_bfloat16* __restrict__ outA, int M) {
  int dst = blockIdx.x * 4 + (threadIdx.x >> 6);
  if (dst >= M) return;
  int t = threadIdx.x & 63;  // channels 4t..4t+3
  int beg = rp[dst], end = rp[dst + 1];
  float acc[4][8];
#pragma unroll
  for (int ch = 0; ch < 4; ch++)
#pragma unroll
    for (int h = 0; h < 8; h++) acc[ch][h] = 0.f;
  int sN = (beg < end) ? col[beg] : 0;
  for (int i = beg; i < end; i++) {
    int s = sN;
    if (i + 1 < end) sN = col[i + 1];
    float4 w0 = *(const float4*)(ex + (size_t)i * 8);
    float4 w1 = *(const float4*)(ex + (size_t)i * 8 + 4);
    union { uint2 u; unsigned short us[4]; } uu;
    uu.u = *(const uint2*)(g2 + (size_t)s * 256 + t * 4);
#pragma unroll
    for (int ch = 0; ch < 4; ch++) {
      float v = bf2f(uu.us[ch]);
      acc[ch][0] += w0.x * v; acc[ch][1] += w0.y * v;
      acc[ch][2] += w0.z * v; acc[ch][3] += w0.w * v;
      acc[ch][4] += w1.x * v; acc[ch][5] += w1.y * v;
      acc[ch][6] += w1.z * v; acc[ch][7] += w1.w * v;
    }
  }
#pragma unroll
  for (int h = 0; h < 8; h++) {
    float inv = invden[dst * 8 + h];
    union { uint2 u; unsigned short us[4]; } pk;
#pragma unroll
    for (int ch = 0; ch < 4; ch++) pk.us[ch] = f2bfu(acc[ch][h] * inv);
    *(uint2*)(outA + (size_t)dst * 2048 + h * 256 + t * 4) = pk.u;
  }
}

extern "C" void kernel_launch(void* const* d_in, const int* in_sizes, int n_in,
                              void* d_out, int out_size, void* d_ws, size_t ws_size,
                              hipStream_t stream) {
  const float* x      = (const float*)d_in[0];
  const int*   ei     = (const int*)d_in[1];
  const float* w_in   = (const float*)d_in[2];
  const float* b_in   = (const float*)d_in[3];
  const float* w_t1   = (const float*)d_in[4];
  const float* b_t1   = (const float*)d_in[5];
  const float* w_t2   = (const float*)d_in[6];
  const float* b_t2   = (const float*)d_in[7];
  const float* w_g1   = (const float*)d_in[8];
  const float* a_src1 = (const float*)d_in[9];
  const float* a_dst1 = (const float*)d_in[10];
  const float* b_g1   = (const float*)d_in[11];
  const float* w_g2   = (const float*)d_in[12];
  const float* a_src2 = (const float*)d_in[13];
  const float* a_dst2 = (const float*)d_in[14];
  const float* b_g2   = (const float*)d_in[15];
  const float* w_g3   = (const float*)d_in[16];
  const float* a_src3 = (const float*)d_in[17];
  const float* a_dst3 = (const float*)d_in[18];
  const float* b_g3   = (const float*)d_in[19];
  const float* w_c1   = (const float*)d_in[20];
  const float* b_c1   = (const float*)d_in[21];
  const float* w_c2   = (const float*)d_in[22];
  const float* b_c2   = (const float*)d_in[23];
  const int M = in_sizes[0] / FIN;  // 20000
  const int E = in_sizes[1] / 2;    // 120000
  (void)n_in; (void)out_size; (void)ws_size;

  char* wsb = (char*)d_ws;
  size_t off = 0;
  auto alloc = [&](size_t bytes) {
    void* p = wsb + off;
    off = (off + bytes + 255) & ~(size_t)255;
    return p;
  };
  typedef __hip_bfloat16 bf;
  bf* xb     = (bf*)alloc((size_t)M * 256 * 2);
  bf* wtin   = (bf*)alloc(256 * 256 * 2);
  bf* wtpair = (bf*)alloc(512 * 256 * 2);
  bf* wtt2   = (bf*)alloc(256 * 256 * 2);
  bf* wtg2   = (bf*)alloc(256 * 256 * 2);
  bf* wtg3s  = (bf*)alloc(256 * 2048 * 2);
  bf* wtc1   = (bf*)alloc(256 * 512 * 2);
  bf* actA   = (bf*)alloc((size_t)M * HID * 2);      // h, later g2
  bf* actB   = (bf*)alloc((size_t)M * HID * 2);      // th, later g1
  bf* hW1    = (bf*)alloc((size_t)M * HID * 2);
  bf* comb   = (bf*)alloc((size_t)M * 2 * HID * 2);  // [g | t]
  bf* hWb    = (bf*)alloc((size_t)M * 2048 * 2);     // agg3 out
  float* as_ = (float*)alloc((size_t)M * 8 * 4);
  float* ad_ = (float*)alloc((size_t)M * 8 * 4);
  float* apj = (float*)alloc(256 * 16 * 4);
  float* exw = (float*)alloc((size_t)(E + M) * 8 * 4);
  float* ivd = (float*)alloc((size_t)M * 8 * 4);
  int* degfill = (int*)alloc((size_t)2 * M * 4);
  int* deg   = degfill;
  int* fillc = degfill + M;
  int* rp    = (int*)alloc((size_t)(M + 1) * 4);
  int* colA  = (int*)alloc((size_t)(E + M) * 4);

  // ---- prep: memset, xcvt+count+logit-init (merged), weight prep ----
  hipMemsetAsync(degfill, 0, (size_t)2 * M * 4, stream);
  int xblocks = (M * 256 + 255) / 256;
  int cblocks = (E + 255) / 256;
  int oblocks = (M * 2 + 255) / 256;
  xc_k<<<xblocks + cblocks + oblocks, 256, 0, stream>>>(x, xb, ei, deg, b_c2, (float*)d_out,
                                                        M, E, xblocks, cblocks);
  wprep_k<<<dim3(8, 16, 15), dim3(32, 8), 0, stream>>>(
      w_in, w_t1, w_g1, w_t2, w_g2, w_c1, w_g3, a_src3, a_dst3,
      wtin, wtpair, wtt2, wtg2, wtc1, wtg3s, apj);

  // ---- CSR build ----
  scan_k<<<1, 1024, 0, stream>>>(deg, rp, M);
  fill_k<<<(E + M + 255) / 256, 256, 0, stream>>>(ei, rp, fillc, colA, E, M);

  int eg = (M + 3) / 4;
  int mg = (M + 63) / 64;

  // h = elu(x @ w_in + b_in) -> actA
  mgemm64_k<2, 0><<<dim3(4, mg), 256, 0, stream>>>(xb, wtin, b_in, actA, HID, M, HID, 256,
                                                   nullptr, nullptr, nullptr, nullptr);
  // dual: th=relu(h@w_t1+b_t1) -> actB ; hW1 = h@w_g1 ; alpha1 -> as_/ad_
  mgemm_dual_k<<<dim3(4, mg), 256, 0, stream>>>(actA, wtpair, b_t1, actB, hW1, M,
                                                a_src1, a_dst1, as_, ad_);
  // t = th @ w_t2 + b_t2 -> comb[:,256:512]
  mgemm64_k<0, 0><<<dim3(4, mg), 256, 0, stream>>>(actB, wtt2, b_t2, comb + HID, 2 * HID,
                                                   M, HID, 256, nullptr, nullptr, nullptr, nullptr);

  // ---- GAT 1 (alpha already computed by dual) ----
  aggf_k<<<eg, 256, 0, stream>>>(rp, colA, hW1, as_, ad_, b_g1, actB, M);  // g1

  // ---- GAT 2: hW2 GEMM + fused alpha2 ----
  mgemm64_k<0, 1><<<dim3(4, mg), 256, 0, stream>>>(actB, wtg2, nullptr, hW1, HID, M, HID, 256,
                                                   a_src2, a_dst2, as_, ad_);
  aggf_k<<<eg, 256, 0, stream>>>(rp, colA, hW1, as_, ad_, b_g2, actA, M);  // g2

  // ---- GAT 3 ----
  alpha3_k<<<(M + 15) / 16, 256, 0, stream>>>(actA, apj, as_, ad_, M);
  esoft_k<<<eg, 256, 0, stream>>>(rp, colA, as_, ad_, exw, ivd, M);
  agg3_k<<<eg, 256, 0, stream>>>(rp, colA, actA, exw, ivd, hWb, M);
  mgemm3_k<<<dim3(4, mg), 256, 0, stream>>>(hWb, wtg3s, b_g3, comb, M);

  // ---- classifier (split-N atomic logits; out pre-initialized in xc_k) ----
  mgemm_cls_k<<<dim3(2, mg), 256, 0, stream>>>(comb, wtc1, b_c1, w_c2, (float*)d_out, M);
}

// Round 15
// 377.915 us; speedup vs baseline: 1.0133x; 1.0133x over previous
//
#include <hip/hip_runtime.h>
#include <hip/hip_bf16.h>
#include <math.h>

// CHRONOS inference. Round 15: mgemm3 reverted to R13 BK=32 (BK=64 dropped
// occupancy 39->29%, net neutral). aggf/agg3 batch 4 edges per iteration
// (independent gathers -> 4x MLP in the dominant dependent-load chain),
// with exact blockwise online-softmax rescale.

#define HID 256
#define HEADS 8
#define FIN 235

typedef __attribute__((ext_vector_type(8))) short short8;
typedef __attribute__((ext_vector_type(4))) float floatx4;

__device__ __forceinline__ float elu_f(float x) { return x > 0.f ? x : __expf(x) - 1.f; }
__device__ __forceinline__ float bf2f(unsigned short u) {
  return __uint_as_float(((unsigned int)u) << 16);
}
__device__ __forceinline__ unsigned short f2bfu(float f) {
  union { __hip_bfloat16 b; unsigned short u; } c;
  c.b = __float2bfloat16(f);
  return c.u;
}

// ---------------- xcvt + edge count + logit init (partitioned grid) ----------------
__global__ void xc_k(const float* __restrict__ x, __hip_bfloat16* __restrict__ xb,
                     const int* __restrict__ ei, int* __restrict__ deg,
                     const float* __restrict__ b2, float* __restrict__ out,
                     int M, int E, int xblocks, int cblocks) {
  int b = blockIdx.x;
  if (b < xblocks) {
    int id = b * 256 + threadIdx.x;
    if (id >= M * 256) return;
    int m = id >> 8, k = id & 255;
    xb[id] = (k < FIN) ? __float2bfloat16(x[(size_t)m * FIN + k]) : __float2bfloat16(0.f);
  } else if (b < xblocks + cblocks) {
    int i = (b - xblocks) * 256 + threadIdx.x;
    if (i < E) atomicAdd(&deg[ei[E + i]], 1);
  } else {
    int i = (b - xblocks - cblocks) * 256 + threadIdx.x;
    if (i < M * 2) out[i] = b2[i & 1];
  }
}

// batched weight transpose+cast (+ aproj at z=14)
__global__ void wprep_k(const float* __restrict__ w_in, const float* __restrict__ w_t1,
                        const float* __restrict__ w_g1, const float* __restrict__ w_t2,
                        const float* __restrict__ w_g2, const float* __restrict__ w_c1,
                        const float* __restrict__ w_g3, const float* __restrict__ a_s3,
                        const float* __restrict__ a_d3, __hip_bfloat16* __restrict__ wtin,
                        __hip_bfloat16* __restrict__ wtpair, __hip_bfloat16* __restrict__ wtt2,
                        __hip_bfloat16* __restrict__ wtg2, __hip_bfloat16* __restrict__ wtc1,
                        __hip_bfloat16* __restrict__ wtg3s, float* __restrict__ apj) {
  __shared__ float t[32][33];
  int z = blockIdx.z;
  if (z == 14) {
    int idx = (blockIdx.y * 8 + blockIdx.x) * 256 + threadIdx.y * 32 + threadIdx.x;
    if (idx < 256 * 16) {
      int k = idx >> 4, o = idx & 15;
      int h = o >> 1;
      const float* av = (o & 1) ? (a_d3 + h * 256) : (a_s3 + h * 256);
      const float* wr = w_g3 + (size_t)k * 2048 + h * 256;
      float s = 0.f;
      for (int c = 0; c < 256; c++) s += wr[c] * av[c];
      apj[idx] = s;
    }
    return;
  }
  const float* src;
  __hip_bfloat16* dst;
  int K, Kpad, Nstride;
  if (z == 5) {
    src = w_c1; dst = wtc1; K = 512; Kpad = 512; Nstride = 256;
  } else {
    if (blockIdx.y >= 8) return;
    switch (z) {
      case 0: src = w_in; dst = wtin; K = FIN; Kpad = 256; Nstride = 256; break;
      case 1: src = w_t1; dst = wtpair; K = 256; Kpad = 256; Nstride = 256; break;
      case 2: src = w_g1; dst = wtpair + 256 * 256; K = 256; Kpad = 256; Nstride = 256; break;
      case 3: src = w_t2; dst = wtt2; K = 256; Kpad = 256; Nstride = 256; break;
      case 4: src = w_g2; dst = wtg2; K = 256; Kpad = 256; Nstride = 256; break;
      default: {
        int h = z - 6;
        src = w_g3 + h * 256; dst = wtg3s + h * 256; K = 256; Kpad = 2048; Nstride = 2048;
      }
    }
  }
  int nb = blockIdx.x * 32, kb = blockIdx.y * 32;
  int tx = threadIdx.x, ty = threadIdx.y;
#pragma unroll
  for (int j = 0; j < 32; j += 8) {
    int k = kb + ty + j;
    t[ty + j][tx] = (k < K) ? src[(size_t)k * Nstride + nb + tx] : 0.f;
  }
  __syncthreads();
#pragma unroll
  for (int j = 0; j < 32; j += 8) {
    int n = nb + ty + j;
    int k = kb + tx;
    dst[(size_t)n * Kpad + k] = __float2bfloat16(t[tx][ty + j]);
  }
}

// ---------------- CSR build ----------------
__global__ void scan_k(const int* __restrict__ deg, int* __restrict__ rp, int n) {
  __shared__ int wsum[16];
  __shared__ int s_carry;
  int tid = threadIdx.x, lane = tid & 63, wid = tid >> 6;
  if (tid == 0) { s_carry = 0; rp[0] = 0; }
  __syncthreads();
  for (int base = 0; base < n; base += 1024) {
    int i = base + tid;
    int x = (i < n) ? (deg[i] + 1) : 0;  // +1 self-loop
#pragma unroll
    for (int off = 1; off < 64; off <<= 1) {
      int y = __shfl_up(x, off);
      if (lane >= off) x += y;
    }
    if (lane == 63) wsum[wid] = x;
    __syncthreads();
    if (wid == 0 && lane < 16) {
      int s = wsum[lane];
#pragma unroll
      for (int off = 1; off < 16; off <<= 1) {
        int y = __shfl_up(s, off);
        if (lane >= off) s += y;
      }
      wsum[lane] = s;
    }
    __syncthreads();
    int offset = s_carry + (wid > 0 ? wsum[wid - 1] : 0);
    if (i < n) rp[i + 1] = offset + x;
    __syncthreads();
    if (tid == 1023) s_carry += wsum[15];
    __syncthreads();
  }
}

__global__ void fill_k(const int* __restrict__ ei, const int* __restrict__ rp,
                       int* __restrict__ fillc, int* __restrict__ colA, int E, int n) {
  int i = blockIdx.x * blockDim.x + threadIdx.x;
  if (i < E) {
    int d = ei[E + i];
    int pos = rp[d] + atomicAdd(&fillc[d], 1);
    colA[pos] = ei[i];
  } else if (i < E + n) {
    int v = i - E;
    int pos = rp[v] + atomicAdd(&fillc[v], 1);
    colA[pos] = v;
  }
}

// ---------------- bf16 MFMA GEMM, TILE 64x64, BK=32 ----------------
// ALPHA: also emit layer-2 attention logits from acc (head = 2*bx + wc).
template <int ACT, int ALPHA>
__global__ __launch_bounds__(256) void mgemm64_k(
    const __hip_bfloat16* __restrict__ A, const __hip_bfloat16* __restrict__ Bt,
    const float* __restrict__ bias, __hip_bfloat16* __restrict__ Cb,
    int ldc, int M, int N, int K, const float* __restrict__ a_s,
    const float* __restrict__ a_d, float* __restrict__ as_, float* __restrict__ ad_) {
  __shared__ short As[64 * 40];
  __shared__ short Bs[64 * 40];
  int tid = threadIdx.x;
  int row0 = blockIdx.y * 64, col0 = blockIdx.x * 64;
  int w = tid >> 6, lane = tid & 63;
  int wr = w >> 1, wc = w & 1;
  int quad = lane >> 4, l16 = lane & 15;
  floatx4 zero = {0.f, 0.f, 0.f, 0.f};
  floatx4 acc[2][2];
#pragma unroll
  for (int i = 0; i < 2; i++)
#pragma unroll
    for (int j = 0; j < 2; j++) acc[i][j] = zero;

  int srow = tid >> 2, sq = tid & 3;
  const __hip_bfloat16* Ap = A + (size_t)(row0 + srow) * K + sq * 8;
  const __hip_bfloat16* Bp = Bt + (size_t)(col0 + srow) * K + sq * 8;
  bool aok = (row0 + srow) < M;

  uint4 a1 = make_uint4(0, 0, 0, 0);
  if (aok) a1 = *(const uint4*)(Ap);
  uint4 b1 = *(const uint4*)(Bp);

  for (int k0 = 0; k0 < K; k0 += 32) {
    __syncthreads();
    *(uint4*)&As[srow * 40 + sq * 8] = a1;
    *(uint4*)&Bs[srow * 40 + sq * 8] = b1;
    int kn = k0 + 32;
    if (kn < K) {
      if (aok) a1 = *(const uint4*)(Ap + kn);
      b1 = *(const uint4*)(Bp + kn);
    }
    __syncthreads();
    short8 fa[2], fb[2];
#pragma unroll
    for (int i = 0; i < 2; i++) {
      fa[i] = *(const short8*)&As[(wr * 32 + i * 16 + l16) * 40 + quad * 8];
      fb[i] = *(const short8*)&Bs[(wc * 32 + i * 16 + l16) * 40 + quad * 8];
    }
#pragma unroll
    for (int mi = 0; mi < 2; mi++)
#pragma unroll
      for (int ni = 0; ni < 2; ni++)
        acc[mi][ni] = __builtin_amdgcn_mfma_f32_16x16x32_bf16(fa[mi], fb[ni], acc[mi][ni], 0, 0, 0);
  }

#pragma unroll
  for (int mi = 0; mi < 2; mi++) {
    int rbase = row0 + wr * 32 + mi * 16 + quad * 4;
#pragma unroll
    for (int ni = 0; ni < 2; ni++) {
      int c = col0 + wc * 32 + ni * 16 + l16;
      float bv = bias ? bias[c] : 0.f;
#pragma unroll
      for (int reg = 0; reg < 4; reg++) {
        int rr = rbase + reg;
        if (rr >= M) continue;
        float v = acc[mi][ni][reg] + bv;
        if (ACT == 1) v = fmaxf(v, 0.f);
        if (ACT == 2) v = elu_f(v);
        Cb[(size_t)rr * ldc + c] = __float2bfloat16(v);
      }
    }
  }

  if (ALPHA) {
    int h = 2 * blockIdx.x + wc;
    float aS0 = a_s[h * 32 + l16], aS1 = a_s[h * 32 + 16 + l16];
    float aD0 = a_d[h * 32 + l16], aD1 = a_d[h * 32 + 16 + l16];
#pragma unroll
    for (int mi = 0; mi < 2; mi++)
#pragma unroll
      for (int reg = 0; reg < 4; reg++) {
        float pS = acc[mi][0][reg] * aS0 + acc[mi][1][reg] * aS1;
        float pD = acc[mi][0][reg] * aD0 + acc[mi][1][reg] * aD1;
#pragma unroll
        for (int off = 1; off < 16; off <<= 1) {
          pS += __shfl_xor(pS, off);
          pD += __shfl_xor(pD, off);
        }
        if (l16 == 0) {
          int r = row0 + wr * 32 + mi * 16 + quad * 4 + reg;
          if (r < M) {
            as_[r * 8 + h] = pS;
            ad_[r * 8 + h] = pD;
          }
        }
      }
  }
}

// ---------------- dual GEMM (N=512): A@[w_t1 | w_g1], split epilogue ----------------
__global__ __launch_bounds__(256) void mgemm_dual_k(
    const __hip_bfloat16* __restrict__ A, const __hip_bfloat16* __restrict__ Bt,
    const float* __restrict__ bias1, __hip_bfloat16* __restrict__ O1,
    __hip_bfloat16* __restrict__ O2, int M, const float* __restrict__ a_s1,
    const float* __restrict__ a_d1, float* __restrict__ as_, float* __restrict__ ad_) {
  const int K = 256;
  __shared__ short As[64 * 40];
  __shared__ short Bs[128 * 40];
  int tid = threadIdx.x;
  int row0 = blockIdx.y * 64, col0 = blockIdx.x * 128;
  int w = tid >> 6, lane = tid & 63;
  int wr = w >> 1, wc = w & 1;
  int quad = lane >> 4, l16 = lane & 15;
  floatx4 zero = {0.f, 0.f, 0.f, 0.f};
  floatx4 acc[2][4];
#pragma unroll
  for (int i = 0; i < 2; i++)
#pragma unroll
    for (int j = 0; j < 4; j++) acc[i][j] = zero;

  int srow = tid >> 2, sq = tid & 3;
  const __hip_bfloat16* Ap = A + (size_t)(row0 + srow) * K + sq * 8;
  const __hip_bfloat16* Bp1 = Bt + (size_t)(col0 + srow) * K + sq * 8;
  const __hip_bfloat16* Bp2 = Bt + (size_t)(col0 + 64 + srow) * K + sq * 8;
  bool aok = (row0 + srow) < M;

  uint4 a1 = make_uint4(0, 0, 0, 0);
  if (aok) a1 = *(const uint4*)(Ap);
  uint4 b1 = *(const uint4*)(Bp1);
  uint4 b2 = *(const uint4*)(Bp2);

  for (int k0 = 0; k0 < K; k0 += 32) {
    __syncthreads();
    *(uint4*)&As[srow * 40 + sq * 8] = a1;
    *(uint4*)&Bs[srow * 40 + sq * 8] = b1;
    *(uint4*)&Bs[(64 + srow) * 40 + sq * 8] = b2;
    int kn = k0 + 32;
    if (kn < K) {
      if (aok) a1 = *(const uint4*)(Ap + kn);
      b1 = *(const uint4*)(Bp1 + kn);
      b2 = *(const uint4*)(Bp2 + kn);
    }
    __syncthreads();
    short8 fa[2], fb[4];
#pragma unroll
    for (int i = 0; i < 2; i++)
      fa[i] = *(const short8*)&As[(wr * 32 + i * 16 + l16) * 40 + quad * 8];
#pragma unroll
    for (int i = 0; i < 4; i++)
      fb[i] = *(const short8*)&Bs[(wc * 64 + i * 16 + l16) * 40 + quad * 8];
#pragma unroll
    for (int mi = 0; mi < 2; mi++)
#pragma unroll
      for (int ni = 0; ni < 4; ni++)
        acc[mi][ni] = __builtin_amdgcn_mfma_f32_16x16x32_bf16(fa[mi], fb[ni], acc[mi][ni], 0, 0, 0);
  }

#pragma unroll
  for (int mi = 0; mi < 2; mi++) {
    int rbase = row0 + wr * 32 + mi * 16 + quad * 4;
#pragma unroll
    for (int ni = 0; ni < 4; ni++) {
      int c = col0 + wc * 64 + ni * 16 + l16;
      bool first = c < 256;
      float bv = first ? bias1[c] : 0.f;
      int cc = first ? c : (c - 256);
#pragma unroll
      for (int reg = 0; reg < 4; reg++) {
        int rr = rbase + reg;
        if (rr >= M) continue;
        float v = acc[mi][ni][reg] + bv;
        if (first) v = fmaxf(v, 0.f);
        __hip_bfloat16* dst = first ? O1 : O2;
        dst[(size_t)rr * 256 + cc] = __float2bfloat16(v);
      }
    }
  }

  if (blockIdx.x >= 2) {
    int hb = (blockIdx.x - 2) * 4 + wc * 2;
    float aSA0 = a_s1[hb * 32 + l16], aSA1 = a_s1[hb * 32 + 16 + l16];
    float aDA0 = a_d1[hb * 32 + l16], aDA1 = a_d1[hb * 32 + 16 + l16];
    float aSB0 = a_s1[(hb + 1) * 32 + l16], aSB1 = a_s1[(hb + 1) * 32 + 16 + l16];
    float aDB0 = a_d1[(hb + 1) * 32 + l16], aDB1 = a_d1[(hb + 1) * 32 + 16 + l16];
#pragma unroll
    for (int mi = 0; mi < 2; mi++)
#pragma unroll
      for (int reg = 0; reg < 4; reg++) {
        float pSA = acc[mi][0][reg] * aSA0 + acc[mi][1][reg] * aSA1;
        float pDA = acc[mi][0][reg] * aDA0 + acc[mi][1][reg] * aDA1;
        float pSB = acc[mi][2][reg] * aSB0 + acc[mi][3][reg] * aSB1;
        float pDB = acc[mi][2][reg] * aDB0 + acc[mi][3][reg] * aDB1;
#pragma unroll
        for (int off = 1; off < 16; off <<= 1) {
          pSA += __shfl_xor(pSA, off);
          pDA += __shfl_xor(pDA, off);
          pSB += __shfl_xor(pSB, off);
          pDB += __shfl_xor(pDB, off);
        }
        if (l16 == 0) {
          int r = row0 + wr * 32 + mi * 16 + quad * 4 + reg;
          if (r < M) {
            as_[r * 8 + hb] = pSA;
            ad_[r * 8 + hb] = pDA;
            as_[r * 8 + hb + 1] = pSB;
            ad_[r * 8 + hb + 1] = pDB;
          }
        }
      }
  }
}

// ---------------- GAT3 GEMM: 64x64 tile, K=2048, head-fold, XCD swizzle (R13) ----------------
__global__ __launch_bounds__(256) void mgemm3_k(
    const __hip_bfloat16* __restrict__ A, const __hip_bfloat16* __restrict__ Bt,
    const float* __restrict__ bias, __hip_bfloat16* __restrict__ comb, int M) {
  const int K = 2048;
  __shared__ short As[64 * 40];
  __shared__ short Bs[64 * 40];
  int tid = threadIdx.x;
  int mg = (M + 63) >> 6;
  int total = mg * 4;
  int F = blockIdx.y * 4 + blockIdx.x;
  int Fmain = (total >> 5) << 5;
  int bx, by;
  if (F < Fmain) {
    by = (F >> 5) * 8 + (F & 7);
    bx = (F >> 3) & 3;
  } else {
    by = ((total >> 5) << 3) + ((F - Fmain) >> 2);
    bx = (F - Fmain) & 3;
  }
  int row0 = by * 64, col0 = bx * 64;
  int w = tid >> 6, lane = tid & 63;
  int wr = w >> 1, wc = w & 1;
  int quad = lane >> 4, l16 = lane & 15;
  floatx4 zero = {0.f, 0.f, 0.f, 0.f};
  floatx4 acc[2][2], sum[2][2];
#pragma unroll
  for (int i = 0; i < 2; i++)
#pragma unroll
    for (int j = 0; j < 2; j++) { acc[i][j] = zero; sum[i][j] = zero; }

  int srow = tid >> 2, sq = tid & 3;
  const __hip_bfloat16* Ap = A + (size_t)(row0 + srow) * K + sq * 8;
  const __hip_bfloat16* Bp = Bt + (size_t)(col0 + srow) * K + sq * 8;
  bool aok = (row0 + srow) < M;

  uint4 a1 = make_uint4(0, 0, 0, 0);
  if (aok) a1 = *(const uint4*)(Ap);
  uint4 b1 = *(const uint4*)(Bp);

  for (int k0 = 0; k0 < K; k0 += 32) {
    __syncthreads();
    *(uint4*)&As[srow * 40 + sq * 8] = a1;
    *(uint4*)&Bs[srow * 40 + sq * 8] = b1;
    int kn = k0 + 32;
    if (kn < K) {
      if (aok) a1 = *(const uint4*)(Ap + kn);
      b1 = *(const uint4*)(Bp + kn);
    }
    __syncthreads();
    short8 fa[2], fb[2];
#pragma unroll
    for (int i = 0; i < 2; i++) {
      fa[i] = *(const short8*)&As[(wr * 32 + i * 16 + l16) * 40 + quad * 8];
      fb[i] = *(const short8*)&Bs[(wc * 32 + i * 16 + l16) * 40 + quad * 8];
    }
#pragma unroll
    for (int mi = 0; mi < 2; mi++)
#pragma unroll
      for (int ni = 0; ni < 2; ni++)
        acc[mi][ni] = __builtin_amdgcn_mfma_f32_16x16x32_bf16(fa[mi], fb[ni], acc[mi][ni], 0, 0, 0);
    if (((k0 + 32) & 255) == 0) {  // head boundary: fold elu(acc + b_h)
      int h = k0 >> 8;
#pragma unroll
      for (int mi = 0; mi < 2; mi++)
#pragma unroll
        for (int ni = 0; ni < 2; ni++) {
          int c = col0 + wc * 32 + ni * 16 + l16;
          float bv = bias[h * 256 + c];
#pragma unroll
          for (int reg = 0; reg < 4; reg++) {
            sum[mi][ni][reg] += elu_f(acc[mi][ni][reg] + bv);
            acc[mi][ni][reg] = 0.f;
          }
        }
    }
  }

#pragma unroll
  for (int mi = 0; mi < 2; mi++) {
    int rbase = row0 + wr * 32 + mi * 16 + quad * 4;
#pragma unroll
    for (int ni = 0; ni < 2; ni++) {
      int c = col0 + wc * 32 + ni * 16 + l16;
#pragma unroll
      for (int reg = 0; reg < 4; reg++) {
        int rr = rbase + reg;
        if (rr >= M) continue;
        comb[(size_t)rr * 512 + c] = __float2bfloat16(sum[mi][ni][reg] * 0.125f);
      }
    }
  }
}

// ---------------- classifier: split-N=2, 64x128 tile, atomic logits ----------------
__global__ __launch_bounds__(256) void mgemm_cls_k(
    const __hip_bfloat16* __restrict__ A, const __hip_bfloat16* __restrict__ Bt,
    const float* __restrict__ bias, const float* __restrict__ w2,
    float* __restrict__ out, int M) {
  const int K = 512;
  __shared__ short As[64 * 40];
  __shared__ short Bs[128 * 40];
  __shared__ float ls[64][2][2];
  int tid = threadIdx.x;
  int row0 = blockIdx.y * 64, col0 = blockIdx.x * 128;
  int w = tid >> 6, lane = tid & 63;
  int wr = w >> 1, wc = w & 1;
  int quad = lane >> 4, l16 = lane & 15;
  floatx4 zero = {0.f, 0.f, 0.f, 0.f};
  floatx4 acc[2][4];
#pragma unroll
  for (int i = 0; i < 2; i++)
#pragma unroll
    for (int j = 0; j < 4; j++) acc[i][j] = zero;

  int srow = tid >> 2, sq = tid & 3;
  const __hip_bfloat16* Ap = A + (size_t)(row0 + srow) * K + sq * 8;
  const __hip_bfloat16* Bp1 = Bt + (size_t)(col0 + srow) * K + sq * 8;
  const __hip_bfloat16* Bp2 = Bt + (size_t)(col0 + 64 + srow) * K + sq * 8;
  bool aok = (row0 + srow) < M;

  uint4 a1 = make_uint4(0, 0, 0, 0);
  if (aok) a1 = *(const uint4*)(Ap);
  uint4 b1 = *(const uint4*)(Bp1);
  uint4 b2 = *(const uint4*)(Bp2);

  for (int k0 = 0; k0 < K; k0 += 32) {
    __syncthreads();
    *(uint4*)&As[srow * 40 + sq * 8] = a1;
    *(uint4*)&Bs[srow * 40 + sq * 8] = b1;
    *(uint4*)&Bs[(64 + srow) * 40 + sq * 8] = b2;
    int kn = k0 + 32;
    if (kn < K) {
      if (aok) a1 = *(const uint4*)(Ap + kn);
      b1 = *(const uint4*)(Bp1 + kn);
      b2 = *(const uint4*)(Bp2 + kn);
    }
    __syncthreads();
    short8 fa[2], fb[4];
#pragma unroll
    for (int i = 0; i < 2; i++)
      fa[i] = *(const short8*)&As[(wr * 32 + i * 16 + l16) * 40 + quad * 8];
#pragma unroll
    for (int i = 0; i < 4; i++)
      fb[i] = *(const short8*)&Bs[(wc * 64 + i * 16 + l16) * 40 + quad * 8];
#pragma unroll
    for (int mi = 0; mi < 2; mi++)
#pragma unroll
      for (int ni = 0; ni < 4; ni++)
        acc[mi][ni] = __builtin_amdgcn_mfma_f32_16x16x32_bf16(fa[mi], fb[ni], acc[mi][ni], 0, 0, 0);
  }

  float p0[2][4], p1[2][4];
#pragma unroll
  for (int mi = 0; mi < 2; mi++)
#pragma unroll
    for (int reg = 0; reg < 4; reg++) { p0[mi][reg] = 0.f; p1[mi][reg] = 0.f; }
#pragma unroll
  for (int mi = 0; mi < 2; mi++)
#pragma unroll
    for (int ni = 0; ni < 4; ni++) {
      int c = col0 + wc * 64 + ni * 16 + l16;
      float bv = bias[c];
      float w20 = w2[c * 2 + 0], w21 = w2[c * 2 + 1];
#pragma unroll
      for (int reg = 0; reg < 4; reg++) {
        float v = fmaxf(acc[mi][ni][reg] + bv, 0.f);
        p0[mi][reg] += v * w20;
        p1[mi][reg] += v * w21;
      }
    }
#pragma unroll
  for (int off = 1; off < 16; off <<= 1)
#pragma unroll
    for (int mi = 0; mi < 2; mi++)
#pragma unroll
      for (int reg = 0; reg < 4; reg++) {
        p0[mi][reg] += __shfl_xor(p0[mi][reg], off);
        p1[mi][reg] += __shfl_xor(p1[mi][reg], off);
      }
  if (l16 == 0) {
#pragma unroll
    for (int mi = 0; mi < 2; mi++)
#pragma unroll
      for (int reg = 0; reg < 4; reg++) {
        int rl = wr * 32 + mi * 16 + quad * 4 + reg;
        ls[rl][wc][0] = p0[mi][reg];
        ls[rl][wc][1] = p1[mi][reg];
      }
  }
  __syncthreads();
  if (tid < 64) {
    int r = row0 + tid;
    if (r < M) {
      atomicAdd(&out[r * 2 + 0], ls[tid][0][0] + ls[tid][1][0]);
      atomicAdd(&out[r * 2 + 1], ls[tid][0][1] + ls[tid][1][1]);
    }
  }
}

// ---------------- alpha3: apj in LDS, vectorized row loads ----------------
__global__ __launch_bounds__(256) void alpha3_k(const __hip_bfloat16* __restrict__ g2,
                                                const float* __restrict__ apj,
                                                float* __restrict__ as_, float* __restrict__ ad_,
                                                int M) {
  __shared__ float sapj[4096];
  int tid = threadIdx.x;
  for (int i = tid; i < 4096; i += 256) sapj[i] = apj[i];
  __syncthreads();
  int nl = tid >> 4, o = tid & 15;
  int n = blockIdx.x * 16 + nl;
  if (n >= M) return;
  const __hip_bfloat16* row = g2 + (size_t)n * 256;
  float s = 0.f;
  for (int cc = 0; cc < 256; cc += 8) {
    short8 v8 = *(const short8*)(row + cc);
#pragma unroll
    for (int j = 0; j < 8; j++)
      s += bf2f((unsigned short)v8[j]) * sapj[(cc + j) * 16 + o];
  }
  if (o & 1) ad_[n * 8 + (o >> 1)] = s;
  else as_[n * 8 + (o >> 1)] = s;
}

// ---------------- fused online-softmax aggregate (GAT1/2), 4-edge batches ----------------
__global__ __launch_bounds__(256) void aggf_k(const int* __restrict__ rp,
                                              const int* __restrict__ col,
                                              const __hip_bfloat16* __restrict__ hW,
                                              const float* __restrict__ as_,
                                              const float* __restrict__ ad_,
                                              const float* __restrict__ bias,
                                              __hip_bfloat16* __restrict__ out, int M) {
  int dst = blockIdx.x * 4 + (threadIdx.x >> 6);
  if (dst >= M) return;
  int t = threadIdx.x & 63;
  int h = t >> 3, c = t << 2;
  int beg = rp[dst], end = rp[dst + 1];
  float adv = ad_[dst * 8 + h];
  float m = -3.4e38f, den = 0.f;
  float a0 = 0.f, a1 = 0.f, a2 = 0.f, a3 = 0.f;
  int i = beg;
  for (; i + 4 <= end; i += 4) {
    int s0 = col[i], s1 = col[i + 1], s2 = col[i + 2], s3 = col[i + 3];
    float e0 = as_[s0 * 8 + h] + adv;
    float e1 = as_[s1 * 8 + h] + adv;
    float e2 = as_[s2 * 8 + h] + adv;
    float e3 = as_[s3 * 8 + h] + adv;
    union { uint2 u; unsigned short us[4]; } v0, v1, v2, v3;
    v0.u = *(const uint2*)(hW + (size_t)s0 * HID + c);
    v1.u = *(const uint2*)(hW + (size_t)s1 * HID + c);
    v2.u = *(const uint2*)(hW + (size_t)s2 * HID + c);
    v3.u = *(const uint2*)(hW + (size_t)s3 * HID + c);
    e0 = e0 > 0.f ? e0 : 0.2f * e0;
    e1 = e1 > 0.f ? e1 : 0.2f * e1;
    e2 = e2 > 0.f ? e2 : 0.2f * e2;
    e3 = e3 > 0.f ? e3 : 0.2f * e3;
    float mb = fmaxf(fmaxf(e0, e1), fmaxf(e2, e3));
    float mn = fmaxf(m, mb);
    float sc = __expf(m - mn);
    float w0 = __expf(e0 - mn), w1 = __expf(e1 - mn);
    float w2 = __expf(e2 - mn), w3 = __expf(e3 - mn);
    m = mn;
    den = den * sc + (w0 + w1 + w2 + w3);
    a0 = a0 * sc + w0 * bf2f(v0.us[0]) + w1 * bf2f(v1.us[0]) + w2 * bf2f(v2.us[0]) + w3 * bf2f(v3.us[0]);
    a1 = a1 * sc + w0 * bf2f(v0.us[1]) + w1 * bf2f(v1.us[1]) + w2 * bf2f(v2.us[1]) + w3 * bf2f(v3.us[1]);
    a2 = a2 * sc + w0 * bf2f(v0.us[2]) + w1 * bf2f(v1.us[2]) + w2 * bf2f(v2.us[2]) + w3 * bf2f(v3.us[2]);
    a3 = a3 * sc + w0 * bf2f(v0.us[3]) + w1 * bf2f(v1.us[3]) + w2 * bf2f(v2.us[3]) + w3 * bf2f(v3.us[3]);
  }
  for (; i < end; i++) {
    int s = col[i];
    float e = as_[s * 8 + h] + adv;
    e = e > 0.f ? e : 0.2f * e;
    float mn = fmaxf(m, e);
    float sc = __expf(m - mn);
    float wgt = __expf(e - mn);
    m = mn;
    union { uint2 u; unsigned short us[4]; } uu;
    uu.u = *(const uint2*)(hW + (size_t)s * HID + c);
    den = den * sc + wgt;
    a0 = a0 * sc + wgt * bf2f(uu.us[0]);
    a1 = a1 * sc + wgt * bf2f(uu.us[1]);
    a2 = a2 * sc + wgt * bf2f(uu.us[2]);
    a3 = a3 * sc + wgt * bf2f(uu.us[3]);
  }
  float inv = 1.f / (den + 1e-16f);
  out[(size_t)dst * HID + c + 0] = __float2bfloat16(elu_f(a0 * inv + bias[c + 0]));
  out[(size_t)dst * HID + c + 1] = __float2bfloat16(elu_f(a1 * inv + bias[c + 1]));
  out[(size_t)dst * HID + c + 2] = __float2bfloat16(elu_f(a2 * inv + bias[c + 2]));
  out[(size_t)dst * HID + c + 3] = __float2bfloat16(elu_f(a3 * inv + bias[c + 3]));
}

// ---------------- edge softmax (GAT3) ----------------
__global__ __launch_bounds__(256) void esoft_k(const int* __restrict__ rp,
                                               const int* __restrict__ col,
                                               const float* __restrict__ as_,
                                               const float* __restrict__ ad_,
                                               float* __restrict__ ex,
                                               float* __restrict__ invden, int M) {
  int dst = blockIdx.x * 4 + (threadIdx.x >> 6);
  if (dst >= M) return;
  int lane = threadIdx.x & 63;
  int es = lane >> 3, h = lane & 7;
  int beg = rp[dst], end = rp[dst + 1];
  float adv = ad_[dst * 8 + h];
  float m = -3.4e38f;
  for (int i = beg + es; i < end; i += 8) {
    float e = as_[col[i] * 8 + h] + adv;
    e = e > 0.f ? e : 0.2f * e;
    m = fmaxf(m, e);
  }
  m = fmaxf(m, __shfl_xor(m, 8));
  m = fmaxf(m, __shfl_xor(m, 16));
  m = fmaxf(m, __shfl_xor(m, 32));
  float den = 0.f;
  for (int i = beg + es; i < end; i += 8) {
    float e = as_[col[i] * 8 + h] + adv;
    e = e > 0.f ? e : 0.2f * e;
    float v = __expf(e - m);
    ex[(size_t)i * 8 + h] = v;
    den += v;
  }
  den += __shfl_xor(den, 8);
  den += __shfl_xor(den, 16);
  den += __shfl_xor(den, 32);
  if (es == 0) invden[dst * 8 + h] = 1.f / (den + 1e-16f);
}

// ---------------- GAT3 aggregate: 4 dsts/block, 64 thr/dst, 2-edge batches ----------------
__global__ __launch_bounds__(256) void agg3_k(const int* __restrict__ rp,
                                              const int* __restrict__ col,
                                              const __hip_bfloat16* __restrict__ g2,
                                              const float* __restrict__ ex,
                                              const float* __restrict__ invden,
                                              __hip_bfloat16* __restrict__ outA, int M) {
  int dst = blockIdx.x * 4 + (threadIdx.x >> 6);
  if (dst >= M) return;
  int t = threadIdx.x & 63;  // channels 4t..4t+3
  int beg = rp[dst], end = rp[dst + 1];
  float acc[4][8];
#pragma unroll
  for (int ch = 0; ch < 4; ch++)
#pragma unroll
    for (int h = 0; h < 8; h++) acc[ch][h] = 0.f;
  int i = beg;
  for (; i + 2 <= end; i += 2) {
    int s0 = col[i], s1 = col[i + 1];
    union { uint2 u; unsigned short us[4]; } u0, u1;
    u0.u = *(const uint2*)(g2 + (size_t)s0 * 256 + t * 4);
    u1.u = *(const uint2*)(g2 + (size_t)s1 * 256 + t * 4);
    float4 wa0 = *(const float4*)(ex + (size_t)i * 8);
    float4 wa1 = *(const float4*)(ex + (size_t)i * 8 + 4);
    float4 wb0 = *(const float4*)(ex + (size_t)(i + 1) * 8);
    float4 wb1 = *(const float4*)(ex + (size_t)(i + 1) * 8 + 4);
#pragma unroll
    for (int ch = 0; ch < 4; ch++) {
      float va = bf2f(u0.us[ch]), vb = bf2f(u1.us[ch]);
      acc[ch][0] += wa0.x * va + wb0.x * vb;
      acc[ch][1] += wa0.y * va + wb0.y * vb;
      acc[ch][2] += wa0.z * va + wb0.z * vb;
      acc[ch][3] += wa0.w * va + wb0.w * vb;
      acc[ch][4] += wa1.x * va + wb1.x * vb;
      acc[ch][5] += wa1.y * va + wb1.y * vb;
      acc[ch][6] += wa1.z * va + wb1.z * vb;
      acc[ch][7] += wa1.w * va + wb1.w * vb;
    }
  }
  for (; i < end; i++) {
    int s = col[i];
    float4 w0 = *(const float4*)(ex + (size_t)i * 8);
    float4 w1 = *(const float4*)(ex + (size_t)i * 8 + 4);
    union { uint2 u; unsigned short us[4]; } uu;
    uu.u = *(const uint2*)(g2 + (size_t)s * 256 + t * 4);
#pragma unroll
    for (int ch = 0; ch < 4; ch++) {
      float v = bf2f(uu.us[ch]);
      acc[ch][0] += w0.x * v; acc[ch][1] += w0.y * v;
      acc[ch][2] += w0.z * v; acc[ch][3] += w0.w * v;
      acc[ch][4] += w1.x * v; acc[ch][5] += w1.y * v;
      acc[ch][6] += w1.z * v; acc[ch][7] += w1.w * v;
    }
  }
#pragma unroll
  for (int h = 0; h < 8; h++) {
    float inv = invden[dst * 8 + h];
    union { uint2 u; unsigned short us[4]; } pk;
#pragma unroll
    for (int ch = 0; ch < 4; ch++) pk.us[ch] = f2bfu(acc[ch][h] * inv);
    *(uint2*)(outA + (size_t)dst * 2048 + h * 256 + t * 4) = pk.u;
  }
}

extern "C" void kernel_launch(void* const* d_in, const int* in_sizes, int n_in,
                              void* d_out, int out_size, void* d_ws, size_t ws_size,
                              hipStream_t stream) {
  const float* x      = (const float*)d_in[0];
  const int*   ei     = (const int*)d_in[1];
  const float* w_in   = (const float*)d_in[2];
  const float* b_in   = (const float*)d_in[3];
  const float* w_t1   = (const float*)d_in[4];
  const float* b_t1   = (const float*)d_in[5];
  const float* w_t2   = (const float*)d_in[6];
  const float* b_t2   = (const float*)d_in[7];
  const float* w_g1   = (const float*)d_in[8];
  const float* a_src1 = (const float*)d_in[9];
  const float* a_dst1 = (const float*)d_in[10];
  const float* b_g1   = (const float*)d_in[11];
  const float* w_g2   = (const float*)d_in[12];
  const float* a_src2 = (const float*)d_in[13];
  const float* a_dst2 = (const float*)d_in[14];
  const float* b_g2   = (const float*)d_in[15];
  const float* w_g3   = (const float*)d_in[16];
  const float* a_src3 = (const float*)d_in[17];
  const float* a_dst3 = (const float*)d_in[18];
  const float* b_g3   = (const float*)d_in[19];
  const float* w_c1   = (const float*)d_in[20];
  const float* b_c1   = (const float*)d_in[21];
  const float* w_c2   = (const float*)d_in[22];
  const float* b_c2   = (const float*)d_in[23];
  const int M = in_sizes[0] / FIN;  // 20000
  const int E = in_sizes[1] / 2;    // 120000
  (void)n_in; (void)out_size; (void)ws_size;

  char* wsb = (char*)d_ws;
  size_t off = 0;
  auto alloc = [&](size_t bytes) {
    void* p = wsb + off;
    off = (off + bytes + 255) & ~(size_t)255;
    return p;
  };
  typedef __hip_bfloat16 bf;
  bf* xb     = (bf*)alloc((size_t)M * 256 * 2);
  bf* wtin   = (bf*)alloc(256 * 256 * 2);
  bf* wtpair = (bf*)alloc(512 * 256 * 2);
  bf* wtt2   = (bf*)alloc(256 * 256 * 2);
  bf* wtg2   = (bf*)alloc(256 * 256 * 2);
  bf* wtg3s  = (bf*)alloc(256 * 2048 * 2);
  bf* wtc1   = (bf*)alloc(256 * 512 * 2);
  bf* actA   = (bf*)alloc((size_t)M * HID * 2);      // h, later g2
  bf* actB   = (bf*)alloc((size_t)M * HID * 2);      // th, later g1
  bf* hW1    = (bf*)alloc((size_t)M * HID * 2);
  bf* comb   = (bf*)alloc((size_t)M * 2 * HID * 2);  // [g | t]
  bf* hWb    = (bf*)alloc((size_t)M * 2048 * 2);     // agg3 out
  float* as_ = (float*)alloc((size_t)M * 8 * 4);
  float* ad_ = (float*)alloc((size_t)M * 8 * 4);
  float* apj = (float*)alloc(256 * 16 * 4);
  float* exw = (float*)alloc((size_t)(E + M) * 8 * 4);
  float* ivd = (float*)alloc((size_t)M * 8 * 4);
  int* degfill = (int*)alloc((size_t)2 * M * 4);
  int* deg   = degfill;
  int* fillc = degfill + M;
  int* rp    = (int*)alloc((size_t)(M + 1) * 4);
  int* colA  = (int*)alloc((size_t)(E + M) * 4);

  // ---- prep: memset, xcvt+count+logit-init (merged), weight prep ----
  hipMemsetAsync(degfill, 0, (size_t)2 * M * 4, stream);
  int xblocks = (M * 256 + 255) / 256;
  int cblocks = (E + 255) / 256;
  int oblocks = (M * 2 + 255) / 256;
  xc_k<<<xblocks + cblocks + oblocks, 256, 0, stream>>>(x, xb, ei, deg, b_c2, (float*)d_out,
                                                        M, E, xblocks, cblocks);
  wprep_k<<<dim3(8, 16, 15), dim3(32, 8), 0, stream>>>(
      w_in, w_t1, w_g1, w_t2, w_g2, w_c1, w_g3, a_src3, a_dst3,
      wtin, wtpair, wtt2, wtg2, wtc1, wtg3s, apj);

  // ---- CSR build ----
  scan_k<<<1, 1024, 0, stream>>>(deg, rp, M);
  fill_k<<<(E + M + 255) / 256, 256, 0, stream>>>(ei, rp, fillc, colA, E, M);

  int eg = (M + 3) / 4;
  int mg = (M + 63) / 64;

  // h = elu(x @ w_in + b_in) -> actA
  mgemm64_k<2, 0><<<dim3(4, mg), 256, 0, stream>>>(xb, wtin, b_in, actA, HID, M, HID, 256,
                                                   nullptr, nullptr, nullptr, nullptr);
  // dual: th=relu(h@w_t1+b_t1) -> actB ; hW1 = h@w_g1 ; alpha1 -> as_/ad_
  mgemm_dual_k<<<dim3(4, mg), 256, 0, stream>>>(actA, wtpair, b_t1, actB, hW1, M,
                                                a_src1, a_dst1, as_, ad_);
  // t = th @ w_t2 + b_t2 -> comb[:,256:512]
  mgemm64_k<0, 0><<<dim3(4, mg), 256, 0, stream>>>(actB, wtt2, b_t2, comb + HID, 2 * HID,
                                                   M, HID, 256, nullptr, nullptr, nullptr, nullptr);

  // ---- GAT 1 (alpha already computed by dual) ----
  aggf_k<<<eg, 256, 0, stream>>>(rp, colA, hW1, as_, ad_, b_g1, actB, M);  // g1

  // ---- GAT 2: hW2 GEMM + fused alpha2 ----
  mgemm64_k<0, 1><<<dim3(4, mg), 256, 0, stream>>>(actB, wtg2, nullptr, hW1, HID, M, HID, 256,
                                                   a_src2, a_dst2, as_, ad_);
  aggf_k<<<eg, 256, 0, stream>>>(rp, colA, hW1, as_, ad_, b_g2, actA, M);  // g2

  // ---- GAT 3 ----
  alpha3_k<<<(M + 15) / 16, 256, 0, stream>>>(actA, apj, as_, ad_, M);
  esoft_k<<<eg, 256, 0, stream>>>(rp, colA, as_, ad_, exw, ivd, M);
  agg3_k<<<eg, 256, 0, stream>>>(rp, colA, actA, exw, ivd, hWb, M);
  mgemm3_k<<<dim3(4, mg), 256, 0, stream>>>(hWb, wtg3s, b_g3, comb, M);

  // ---- classifier (split-N atomic logits; out pre-initialized in xc_k) ----
  mgemm_cls_k<<<dim3(2, mg), 256, 0, stream>>>(comb, wtc1, b_c1, w_c2, (float*)d_out, M);
}

// Round 16
// 369.565 us; speedup vs baseline: 1.0362x; 1.0226x over previous
//
#include <hip/hip_runtime.h>
#include <hip/hip_bf16.h>
#include <math.h>

// CHRONOS inference. Round 16: partitioned-grid merges of independent
// dispatch pairs — fusedA (in-proj GEMM || CSR fill), fusedB (t2 GEMM ||
// aggf GAT1) — removing 2 launch gaps and co-scheduling MFMA work under the
// latency-bound gather kernel. agg3 batches 4 edges (match aggf). Rest = R15.

#define HID 256
#define HEADS 8
#define FIN 235

typedef __attribute__((ext_vector_type(8))) short short8;
typedef __attribute__((ext_vector_type(4))) float floatx4;

__device__ __forceinline__ float elu_f(float x) { return x > 0.f ? x : __expf(x) - 1.f; }
__device__ __forceinline__ float bf2f(unsigned short u) {
  return __uint_as_float(((unsigned int)u) << 16);
}
__device__ __forceinline__ unsigned short f2bfu(float f) {
  union { __hip_bfloat16 b; unsigned short u; } c;
  c.b = __float2bfloat16(f);
  return c.u;
}

// ---------------- xcvt + edge count + logit init (partitioned grid) ----------------
__global__ void xc_k(const float* __restrict__ x, __hip_bfloat16* __restrict__ xb,
                     const int* __restrict__ ei, int* __restrict__ deg,
                     const float* __restrict__ b2, float* __restrict__ out,
                     int M, int E, int xblocks, int cblocks) {
  int b = blockIdx.x;
  if (b < xblocks) {
    int id = b * 256 + threadIdx.x;
    if (id >= M * 256) return;
    int m = id >> 8, k = id & 255;
    xb[id] = (k < FIN) ? __float2bfloat16(x[(size_t)m * FIN + k]) : __float2bfloat16(0.f);
  } else if (b < xblocks + cblocks) {
    int i = (b - xblocks) * 256 + threadIdx.x;
    if (i < E) atomicAdd(&deg[ei[E + i]], 1);
  } else {
    int i = (b - xblocks - cblocks) * 256 + threadIdx.x;
    if (i < M * 2) out[i] = b2[i & 1];
  }
}

// batched weight transpose+cast (+ aproj at z=14)
__global__ void wprep_k(const float* __restrict__ w_in, const float* __restrict__ w_t1,
                        const float* __restrict__ w_g1, const float* __restrict__ w_t2,
                        const float* __restrict__ w_g2, const float* __restrict__ w_c1,
                        const float* __restrict__ w_g3, const float* __restrict__ a_s3,
                        const float* __restrict__ a_d3, __hip_bfloat16* __restrict__ wtin,
                        __hip_bfloat16* __restrict__ wtpair, __hip_bfloat16* __restrict__ wtt2,
                        __hip_bfloat16* __restrict__ wtg2, __hip_bfloat16* __restrict__ wtc1,
                        __hip_bfloat16* __restrict__ wtg3s, float* __restrict__ apj) {
  __shared__ float t[32][33];
  int z = blockIdx.z;
  if (z == 14) {
    int idx = (blockIdx.y * 8 + blockIdx.x) * 256 + threadIdx.y * 32 + threadIdx.x;
    if (idx < 256 * 16) {
      int k = idx >> 4, o = idx & 15;
      int h = o >> 1;
      const float* av = (o & 1) ? (a_d3 + h * 256) : (a_s3 + h * 256);
      const float* wr = w_g3 + (size_t)k * 2048 + h * 256;
      float s = 0.f;
      for (int c = 0; c < 256; c++) s += wr[c] * av[c];
      apj[idx] = s;
    }
    return;
  }
  const float* src;
  __hip_bfloat16* dst;
  int K, Kpad, Nstride;
  if (z == 5) {
    src = w_c1; dst = wtc1; K = 512; Kpad = 512; Nstride = 256;
  } else {
    if (blockIdx.y >= 8) return;
    switch (z) {
      case 0: src = w_in; dst = wtin; K = FIN; Kpad = 256; Nstride = 256; break;
      case 1: src = w_t1; dst = wtpair; K = 256; Kpad = 256; Nstride = 256; break;
      case 2: src = w_g1; dst = wtpair + 256 * 256; K = 256; Kpad = 256; Nstride = 256; break;
      case 3: src = w_t2; dst = wtt2; K = 256; Kpad = 256; Nstride = 256; break;
      case 4: src = w_g2; dst = wtg2; K = 256; Kpad = 256; Nstride = 256; break;
      default: {
        int h = z - 6;
        src = w_g3 + h * 256; dst = wtg3s + h * 256; K = 256; Kpad = 2048; Nstride = 2048;
      }
    }
  }
  int nb = blockIdx.x * 32, kb = blockIdx.y * 32;
  int tx = threadIdx.x, ty = threadIdx.y;
#pragma unroll
  for (int j = 0; j < 32; j += 8) {
    int k = kb + ty + j;
    t[ty + j][tx] = (k < K) ? src[(size_t)k * Nstride + nb + tx] : 0.f;
  }
  __syncthreads();
#pragma unroll
  for (int j = 0; j < 32; j += 8) {
    int n = nb + ty + j;
    int k = kb + tx;
    dst[(size_t)n * Kpad + k] = __float2bfloat16(t[tx][ty + j]);
  }
}

// ---------------- CSR build ----------------
__global__ void scan_k(const int* __restrict__ deg, int* __restrict__ rp, int n) {
  __shared__ int wsum[16];
  __shared__ int s_carry;
  int tid = threadIdx.x, lane = tid & 63, wid = tid >> 6;
  if (tid == 0) { s_carry = 0; rp[0] = 0; }
  __syncthreads();
  for (int base = 0; base < n; base += 1024) {
    int i = base + tid;
    int x = (i < n) ? (deg[i] + 1) : 0;  // +1 self-loop
#pragma unroll
    for (int off = 1; off < 64; off <<= 1) {
      int y = __shfl_up(x, off);
      if (lane >= off) x += y;
    }
    if (lane == 63) wsum[wid] = x;
    __syncthreads();
    if (wid == 0 && lane < 16) {
      int s = wsum[lane];
#pragma unroll
      for (int off = 1; off < 16; off <<= 1) {
        int y = __shfl_up(s, off);
        if (lane >= off) s += y;
      }
      wsum[lane] = s;
    }
    __syncthreads();
    int offset = s_carry + (wid > 0 ? wsum[wid - 1] : 0);
    if (i < n) rp[i + 1] = offset + x;
    __syncthreads();
    if (tid == 1023) s_carry += wsum[15];
    __syncthreads();
  }
}

// ---------------- GEMM 64x64 body (device fn), LDS passed in ----------------
template <int ACT, int ALPHA>
__device__ __forceinline__ void gemm64_body(
    short* As, short* Bs, const __hip_bfloat16* __restrict__ A,
    const __hip_bfloat16* __restrict__ Bt, const float* __restrict__ bias,
    __hip_bfloat16* __restrict__ Cb, int ldc, int M, int K, int bx, int by,
    const float* __restrict__ a_s, const float* __restrict__ a_d,
    float* __restrict__ as_, float* __restrict__ ad_) {
  int tid = threadIdx.x;
  int row0 = by * 64, col0 = bx * 64;
  int w = tid >> 6, lane = tid & 63;
  int wr = w >> 1, wc = w & 1;
  int quad = lane >> 4, l16 = lane & 15;
  floatx4 zero = {0.f, 0.f, 0.f, 0.f};
  floatx4 acc[2][2];
#pragma unroll
  for (int i = 0; i < 2; i++)
#pragma unroll
    for (int j = 0; j < 2; j++) acc[i][j] = zero;

  int srow = tid >> 2, sq = tid & 3;
  const __hip_bfloat16* Ap = A + (size_t)(row0 + srow) * K + sq * 8;
  const __hip_bfloat16* Bp = Bt + (size_t)(col0 + srow) * K + sq * 8;
  bool aok = (row0 + srow) < M;

  uint4 a1 = make_uint4(0, 0, 0, 0);
  if (aok) a1 = *(const uint4*)(Ap);
  uint4 b1 = *(const uint4*)(Bp);

  for (int k0 = 0; k0 < K; k0 += 32) {
    __syncthreads();
    *(uint4*)&As[srow * 40 + sq * 8] = a1;
    *(uint4*)&Bs[srow * 40 + sq * 8] = b1;
    int kn = k0 + 32;
    if (kn < K) {
      if (aok) a1 = *(const uint4*)(Ap + kn);
      b1 = *(const uint4*)(Bp + kn);
    }
    __syncthreads();
    short8 fa[2], fb[2];
#pragma unroll
    for (int i = 0; i < 2; i++) {
      fa[i] = *(const short8*)&As[(wr * 32 + i * 16 + l16) * 40 + quad * 8];
      fb[i] = *(const short8*)&Bs[(wc * 32 + i * 16 + l16) * 40 + quad * 8];
    }
#pragma unroll
    for (int mi = 0; mi < 2; mi++)
#pragma unroll
      for (int ni = 0; ni < 2; ni++)
        acc[mi][ni] = __builtin_amdgcn_mfma_f32_16x16x32_bf16(fa[mi], fb[ni], acc[mi][ni], 0, 0, 0);
  }

#pragma unroll
  for (int mi = 0; mi < 2; mi++) {
    int rbase = row0 + wr * 32 + mi * 16 + quad * 4;
#pragma unroll
    for (int ni = 0; ni < 2; ni++) {
      int c = col0 + wc * 32 + ni * 16 + l16;
      float bv = bias ? bias[c] : 0.f;
#pragma unroll
      for (int reg = 0; reg < 4; reg++) {
        int rr = rbase + reg;
        if (rr >= M) continue;
        float v = acc[mi][ni][reg] + bv;
        if (ACT == 1) v = fmaxf(v, 0.f);
        if (ACT == 2) v = elu_f(v);
        Cb[(size_t)rr * ldc + c] = __float2bfloat16(v);
      }
    }
  }

  if (ALPHA) {
    int h = 2 * bx + wc;
    float aS0 = a_s[h * 32 + l16], aS1 = a_s[h * 32 + 16 + l16];
    float aD0 = a_d[h * 32 + l16], aD1 = a_d[h * 32 + 16 + l16];
#pragma unroll
    for (int mi = 0; mi < 2; mi++)
#pragma unroll
      for (int reg = 0; reg < 4; reg++) {
        float pS = acc[mi][0][reg] * aS0 + acc[mi][1][reg] * aS1;
        float pD = acc[mi][0][reg] * aD0 + acc[mi][1][reg] * aD1;
#pragma unroll
        for (int off = 1; off < 16; off <<= 1) {
          pS += __shfl_xor(pS, off);
          pD += __shfl_xor(pD, off);
        }
        if (l16 == 0) {
          int r = row0 + wr * 32 + mi * 16 + quad * 4 + reg;
          if (r < M) {
            as_[r * 8 + h] = pS;
            ad_[r * 8 + h] = pD;
          }
        }
      }
  }
}

// ---------------- aggf body (device fn): online softmax, 4-edge batches ----------------
__device__ __forceinline__ void aggf_body(
    const int* __restrict__ rp, const int* __restrict__ col,
    const __hip_bfloat16* __restrict__ hW, const float* __restrict__ as_,
    const float* __restrict__ ad_, const float* __restrict__ bias,
    __hip_bfloat16* __restrict__ out, int M, int blk) {
  int dst = blk * 4 + (threadIdx.x >> 6);
  if (dst >= M) return;
  int t = threadIdx.x & 63;
  int h = t >> 3, c = t << 2;
  int beg = rp[dst], end = rp[dst + 1];
  float adv = ad_[dst * 8 + h];
  float m = -3.4e38f, den = 0.f;
  float a0 = 0.f, a1 = 0.f, a2 = 0.f, a3 = 0.f;
  int i = beg;
  for (; i + 4 <= end; i += 4) {
    int s0 = col[i], s1 = col[i + 1], s2 = col[i + 2], s3 = col[i + 3];
    float e0 = as_[s0 * 8 + h] + adv;
    float e1 = as_[s1 * 8 + h] + adv;
    float e2 = as_[s2 * 8 + h] + adv;
    float e3 = as_[s3 * 8 + h] + adv;
    union { uint2 u; unsigned short us[4]; } v0, v1, v2, v3;
    v0.u = *(const uint2*)(hW + (size_t)s0 * HID + c);
    v1.u = *(const uint2*)(hW + (size_t)s1 * HID + c);
    v2.u = *(const uint2*)(hW + (size_t)s2 * HID + c);
    v3.u = *(const uint2*)(hW + (size_t)s3 * HID + c);
    e0 = e0 > 0.f ? e0 : 0.2f * e0;
    e1 = e1 > 0.f ? e1 : 0.2f * e1;
    e2 = e2 > 0.f ? e2 : 0.2f * e2;
    e3 = e3 > 0.f ? e3 : 0.2f * e3;
    float mb = fmaxf(fmaxf(e0, e1), fmaxf(e2, e3));
    float mn = fmaxf(m, mb);
    float sc = __expf(m - mn);
    float w0 = __expf(e0 - mn), w1 = __expf(e1 - mn);
    float w2 = __expf(e2 - mn), w3 = __expf(e3 - mn);
    m = mn;
    den = den * sc + (w0 + w1 + w2 + w3);
    a0 = a0 * sc + w0 * bf2f(v0.us[0]) + w1 * bf2f(v1.us[0]) + w2 * bf2f(v2.us[0]) + w3 * bf2f(v3.us[0]);
    a1 = a1 * sc + w0 * bf2f(v0.us[1]) + w1 * bf2f(v1.us[1]) + w2 * bf2f(v2.us[1]) + w3 * bf2f(v3.us[1]);
    a2 = a2 * sc + w0 * bf2f(v0.us[2]) + w1 * bf2f(v1.us[2]) + w2 * bf2f(v2.us[2]) + w3 * bf2f(v3.us[2]);
    a3 = a3 * sc + w0 * bf2f(v0.us[3]) + w1 * bf2f(v1.us[3]) + w2 * bf2f(v2.us[3]) + w3 * bf2f(v3.us[3]);
  }
  for (; i < end; i++) {
    int s = col[i];
    float e = as_[s * 8 + h] + adv;
    e = e > 0.f ? e : 0.2f * e;
    float mn = fmaxf(m, e);
    float sc = __expf(m - mn);
    float wgt = __expf(e - mn);
    m = mn;
    union { uint2 u; unsigned short us[4]; } uu;
    uu.u = *(const uint2*)(hW + (size_t)s * HID + c);
    den = den * sc + wgt;
    a0 = a0 * sc + wgt * bf2f(uu.us[0]);
    a1 = a1 * sc + wgt * bf2f(uu.us[1]);
    a2 = a2 * sc + wgt * bf2f(uu.us[2]);
    a3 = a3 * sc + wgt * bf2f(uu.us[3]);
  }
  float inv = 1.f / (den + 1e-16f);
  out[(size_t)dst * HID + c + 0] = __float2bfloat16(elu_f(a0 * inv + bias[c + 0]));
  out[(size_t)dst * HID + c + 1] = __float2bfloat16(elu_f(a1 * inv + bias[c + 1]));
  out[(size_t)dst * HID + c + 2] = __float2bfloat16(elu_f(a2 * inv + bias[c + 2]));
  out[(size_t)dst * HID + c + 3] = __float2bfloat16(elu_f(a3 * inv + bias[c + 3]));
}

// ---------------- fusedA: in-proj GEMM || CSR fill ----------------
__global__ __launch_bounds__(256) void fusedA_k(
    const __hip_bfloat16* __restrict__ xb, const __hip_bfloat16* __restrict__ wtin,
    const float* __restrict__ b_in, __hip_bfloat16* __restrict__ actA,
    const int* __restrict__ ei, const int* __restrict__ rp, int* __restrict__ fillc,
    int* __restrict__ colA, int M, int E, int gemmBlocks) {
  __shared__ short As[64 * 40];
  __shared__ short Bs[64 * 40];
  int b = blockIdx.x;
  if (b < gemmBlocks) {
    gemm64_body<2, 0>(As, Bs, xb, wtin, b_in, actA, HID, M, 256, b & 3, b >> 2,
                      nullptr, nullptr, nullptr, nullptr);
  } else {
    int i = (b - gemmBlocks) * 256 + threadIdx.x;
    if (i < E) {
      int d = ei[E + i];
      int pos = rp[d] + atomicAdd(&fillc[d], 1);
      colA[pos] = ei[i];
    } else if (i < E + M) {
      int v = i - E;
      int pos = rp[v] + atomicAdd(&fillc[v], 1);
      colA[pos] = v;
    }
  }
}

// ---------------- fusedB: t2 GEMM || aggf GAT1 ----------------
__global__ __launch_bounds__(256) void fusedB_k(
    const __hip_bfloat16* __restrict__ actB, const __hip_bfloat16* __restrict__ wtt2,
    const float* __restrict__ b_t2, __hip_bfloat16* __restrict__ combT,
    const int* __restrict__ rp, const int* __restrict__ col,
    const __hip_bfloat16* __restrict__ hW1, const float* __restrict__ as_,
    const float* __restrict__ ad_, const float* __restrict__ b_g1,
    __hip_bfloat16* __restrict__ g1, int M, int gemmBlocks) {
  __shared__ short As[64 * 40];
  __shared__ short Bs[64 * 40];
  int b = blockIdx.x;
  if (b < gemmBlocks) {
    gemm64_body<0, 0>(As, Bs, actB, wtt2, b_t2, combT, 2 * HID, M, 256, b & 3, b >> 2,
                      nullptr, nullptr, nullptr, nullptr);
  } else {
    aggf_body(rp, col, hW1, as_, ad_, b_g1, g1, M, b - gemmBlocks);
  }
}

// ---------------- standalone mgemm64 (dual-alpha users) ----------------
template <int ACT, int ALPHA>
__global__ __launch_bounds__(256) void mgemm64_k(
    const __hip_bfloat16* __restrict__ A, const __hip_bfloat16* __restrict__ Bt,
    const float* __restrict__ bias, __hip_bfloat16* __restrict__ Cb,
    int ldc, int M, int N, int K, const float* __restrict__ a_s,
    const float* __restrict__ a_d, float* __restrict__ as_, float* __restrict__ ad_) {
  __shared__ short As[64 * 40];
  __shared__ short Bs[64 * 40];
  gemm64_body<ACT, ALPHA>(As, Bs, A, Bt, bias, Cb, ldc, M, K, blockIdx.x, blockIdx.y,
                          a_s, a_d, as_, ad_);
}

// ---------------- standalone aggf ----------------
__global__ __launch_bounds__(256) void aggf_k(const int* __restrict__ rp,
                                              const int* __restrict__ col,
                                              const __hip_bfloat16* __restrict__ hW,
                                              const float* __restrict__ as_,
                                              const float* __restrict__ ad_,
                                              const float* __restrict__ bias,
                                              __hip_bfloat16* __restrict__ out, int M) {
  aggf_body(rp, col, hW, as_, ad_, bias, out, M, blockIdx.x);
}

// ---------------- dual GEMM (N=512): A@[w_t1 | w_g1], split epilogue ----------------
__global__ __launch_bounds__(256) void mgemm_dual_k(
    const __hip_bfloat16* __restrict__ A, const __hip_bfloat16* __restrict__ Bt,
    const float* __restrict__ bias1, __hip_bfloat16* __restrict__ O1,
    __hip_bfloat16* __restrict__ O2, int M, const float* __restrict__ a_s1,
    const float* __restrict__ a_d1, float* __restrict__ as_, float* __restrict__ ad_) {
  const int K = 256;
  __shared__ short As[64 * 40];
  __shared__ short Bs[128 * 40];
  int tid = threadIdx.x;
  int row0 = blockIdx.y * 64, col0 = blockIdx.x * 128;
  int w = tid >> 6, lane = tid & 63;
  int wr = w >> 1, wc = w & 1;
  int quad = lane >> 4, l16 = lane & 15;
  floatx4 zero = {0.f, 0.f, 0.f, 0.f};
  floatx4 acc[2][4];
#pragma unroll
  for (int i = 0; i < 2; i++)
#pragma unroll
    for (int j = 0; j < 4; j++) acc[i][j] = zero;

  int srow = tid >> 2, sq = tid & 3;
  const __hip_bfloat16* Ap = A + (size_t)(row0 + srow) * K + sq * 8;
  const __hip_bfloat16* Bp1 = Bt + (size_t)(col0 + srow) * K + sq * 8;
  const __hip_bfloat16* Bp2 = Bt + (size_t)(col0 + 64 + srow) * K + sq * 8;
  bool aok = (row0 + srow) < M;

  uint4 a1 = make_uint4(0, 0, 0, 0);
  if (aok) a1 = *(const uint4*)(Ap);
  uint4 b1 = *(const uint4*)(Bp1);
  uint4 b2 = *(const uint4*)(Bp2);

  for (int k0 = 0; k0 < K; k0 += 32) {
    __syncthreads();
    *(uint4*)&As[srow * 40 + sq * 8] = a1;
    *(uint4*)&Bs[srow * 40 + sq * 8] = b1;
    *(uint4*)&Bs[(64 + srow) * 40 + sq * 8] = b2;
    int kn = k0 + 32;
    if (kn < K) {
      if (aok) a1 = *(const uint4*)(Ap + kn);
      b1 = *(const uint4*)(Bp1 + kn);
      b2 = *(const uint4*)(Bp2 + kn);
    }
    __syncthreads();
    short8 fa[2], fb[4];
#pragma unroll
    for (int i = 0; i < 2; i++)
      fa[i] = *(const short8*)&As[(wr * 32 + i * 16 + l16) * 40 + quad * 8];
#pragma unroll
    for (int i = 0; i < 4; i++)
      fb[i] = *(const short8*)&Bs[(wc * 64 + i * 16 + l16) * 40 + quad * 8];
#pragma unroll
    for (int mi = 0; mi < 2; mi++)
#pragma unroll
      for (int ni = 0; ni < 4; ni++)
        acc[mi][ni] = __builtin_amdgcn_mfma_f32_16x16x32_bf16(fa[mi], fb[ni], acc[mi][ni], 0, 0, 0);
  }

#pragma unroll
  for (int mi = 0; mi < 2; mi++) {
    int rbase = row0 + wr * 32 + mi * 16 + quad * 4;
#pragma unroll
    for (int ni = 0; ni < 4; ni++) {
      int c = col0 + wc * 64 + ni * 16 + l16;
      bool first = c < 256;
      float bv = first ? bias1[c] : 0.f;
      int cc = first ? c : (c - 256);
#pragma unroll
      for (int reg = 0; reg < 4; reg++) {
        int rr = rbase + reg;
        if (rr >= M) continue;
        float v = acc[mi][ni][reg] + bv;
        if (first) v = fmaxf(v, 0.f);
        __hip_bfloat16* dst = first ? O1 : O2;
        dst[(size_t)rr * 256 + cc] = __float2bfloat16(v);
      }
    }
  }

  if (blockIdx.x >= 2) {
    int hb = (blockIdx.x - 2) * 4 + wc * 2;
    float aSA0 = a_s1[hb * 32 + l16], aSA1 = a_s1[hb * 32 + 16 + l16];
    float aDA0 = a_d1[hb * 32 + l16], aDA1 = a_d1[hb * 32 + 16 + l16];
    float aSB0 = a_s1[(hb + 1) * 32 + l16], aSB1 = a_s1[(hb + 1) * 32 + 16 + l16];
    float aDB0 = a_d1[(hb + 1) * 32 + l16], aDB1 = a_d1[(hb + 1) * 32 + 16 + l16];
#pragma unroll
    for (int mi = 0; mi < 2; mi++)
#pragma unroll
      for (int reg = 0; reg < 4; reg++) {
        float pSA = acc[mi][0][reg] * aSA0 + acc[mi][1][reg] * aSA1;
        float pDA = acc[mi][0][reg] * aDA0 + acc[mi][1][reg] * aDA1;
        float pSB = acc[mi][2][reg] * aSB0 + acc[mi][3][reg] * aSB1;
        float pDB = acc[mi][2][reg] * aDB0 + acc[mi][3][reg] * aDB1;
#pragma unroll
        for (int off = 1; off < 16; off <<= 1) {
          pSA += __shfl_xor(pSA, off);
          pDA += __shfl_xor(pDA, off);
          pSB += __shfl_xor(pSB, off);
          pDB += __shfl_xor(pDB, off);
        }
        if (l16 == 0) {
          int r = row0 + wr * 32 + mi * 16 + quad * 4 + reg;
          if (r < M) {
            as_[r * 8 + hb] = pSA;
            ad_[r * 8 + hb] = pDA;
            as_[r * 8 + hb + 1] = pSB;
            ad_[r * 8 + hb + 1] = pDB;
          }
        }
      }
  }
}

// ---------------- GAT3 GEMM: 64x64 tile, K=2048, head-fold, XCD swizzle ----------------
__global__ __launch_bounds__(256) void mgemm3_k(
    const __hip_bfloat16* __restrict__ A, const __hip_bfloat16* __restrict__ Bt,
    const float* __restrict__ bias, __hip_bfloat16* __restrict__ comb, int M) {
  const int K = 2048;
  __shared__ short As[64 * 40];
  __shared__ short Bs[64 * 40];
  int tid = threadIdx.x;
  int mg = (M + 63) >> 6;
  int total = mg * 4;
  int F = blockIdx.y * 4 + blockIdx.x;
  int Fmain = (total >> 5) << 5;
  int bx, by;
  if (F < Fmain) {
    by = (F >> 5) * 8 + (F & 7);
    bx = (F >> 3) & 3;
  } else {
    by = ((total >> 5) << 3) + ((F - Fmain) >> 2);
    bx = (F - Fmain) & 3;
  }
  int row0 = by * 64, col0 = bx * 64;
  int w = tid >> 6, lane = tid & 63;
  int wr = w >> 1, wc = w & 1;
  int quad = lane >> 4, l16 = lane & 15;
  floatx4 zero = {0.f, 0.f, 0.f, 0.f};
  floatx4 acc[2][2], sum[2][2];
#pragma unroll
  for (int i = 0; i < 2; i++)
#pragma unroll
    for (int j = 0; j < 2; j++) { acc[i][j] = zero; sum[i][j] = zero; }

  int srow = tid >> 2, sq = tid & 3;
  const __hip_bfloat16* Ap = A + (size_t)(row0 + srow) * K + sq * 8;
  const __hip_bfloat16* Bp = Bt + (size_t)(col0 + srow) * K + sq * 8;
  bool aok = (row0 + srow) < M;

  uint4 a1 = make_uint4(0, 0, 0, 0);
  if (aok) a1 = *(const uint4*)(Ap);
  uint4 b1 = *(const uint4*)(Bp);

  for (int k0 = 0; k0 < K; k0 += 32) {
    __syncthreads();
    *(uint4*)&As[srow * 40 + sq * 8] = a1;
    *(uint4*)&Bs[srow * 40 + sq * 8] = b1;
    int kn = k0 + 32;
    if (kn < K) {
      if (aok) a1 = *(const uint4*)(Ap + kn);
      b1 = *(const uint4*)(Bp + kn);
    }
    __syncthreads();
    short8 fa[2], fb[2];
#pragma unroll
    for (int i = 0; i < 2; i++) {
      fa[i] = *(const short8*)&As[(wr * 32 + i * 16 + l16) * 40 + quad * 8];
      fb[i] = *(const short8*)&Bs[(wc * 32 + i * 16 + l16) * 40 + quad * 8];
    }
#pragma unroll
    for (int mi = 0; mi < 2; mi++)
#pragma unroll
      for (int ni = 0; ni < 2; ni++)
        acc[mi][ni] = __builtin_amdgcn_mfma_f32_16x16x32_bf16(fa[mi], fb[ni], acc[mi][ni], 0, 0, 0);
    if (((k0 + 32) & 255) == 0) {  // head boundary: fold elu(acc + b_h)
      int h = k0 >> 8;
#pragma unroll
      for (int mi = 0; mi < 2; mi++)
#pragma unroll
        for (int ni = 0; ni < 2; ni++) {
          int c = col0 + wc * 32 + ni * 16 + l16;
          float bv = bias[h * 256 + c];
#pragma unroll
          for (int reg = 0; reg < 4; reg++) {
            sum[mi][ni][reg] += elu_f(acc[mi][ni][reg] + bv);
            acc[mi][ni][reg] = 0.f;
          }
        }
    }
  }

#pragma unroll
  for (int mi = 0; mi < 2; mi++) {
    int rbase = row0 + wr * 32 + mi * 16 + quad * 4;
#pragma unroll
    for (int ni = 0; ni < 2; ni++) {
      int c = col0 + wc * 32 + ni * 16 + l16;
#pragma unroll
      for (int reg = 0; reg < 4; reg++) {
        int rr = rbase + reg;
        if (rr >= M) continue;
        comb[(size_t)rr * 512 + c] = __float2bfloat16(sum[mi][ni][reg] * 0.125f);
      }
    }
  }
}

// ---------------- classifier: split-N=2, 64x128 tile, atomic logits ----------------
__global__ __launch_bounds__(256) void mgemm_cls_k(
    const __hip_bfloat16* __restrict__ A, const __hip_bfloat16* __restrict__ Bt,
    const float* __restrict__ bias, const float* __restrict__ w2,
    float* __restrict__ out, int M) {
  const int K = 512;
  __shared__ short As[64 * 40];
  __shared__ short Bs[128 * 40];
  __shared__ float ls[64][2][2];
  int tid = threadIdx.x;
  int row0 = blockIdx.y * 64, col0 = blockIdx.x * 128;
  int w = tid >> 6, lane = tid & 63;
  int wr = w >> 1, wc = w & 1;
  int quad = lane >> 4, l16 = lane & 15;
  floatx4 zero = {0.f, 0.f, 0.f, 0.f};
  floatx4 acc[2][4];
#pragma unroll
  for (int i = 0; i < 2; i++)
#pragma unroll
    for (int j = 0; j < 4; j++) acc[i][j] = zero;

  int srow = tid >> 2, sq = tid & 3;
  const __hip_bfloat16* Ap = A + (size_t)(row0 + srow) * K + sq * 8;
  const __hip_bfloat16* Bp1 = Bt + (size_t)(col0 + srow) * K + sq * 8;
  const __hip_bfloat16* Bp2 = Bt + (size_t)(col0 + 64 + srow) * K + sq * 8;
  bool aok = (row0 + srow) < M;

  uint4 a1 = make_uint4(0, 0, 0, 0);
  if (aok) a1 = *(const uint4*)(Ap);
  uint4 b1 = *(const uint4*)(Bp1);
  uint4 b2 = *(const uint4*)(Bp2);

  for (int k0 = 0; k0 < K; k0 += 32) {
    __syncthreads();
    *(uint4*)&As[srow * 40 + sq * 8] = a1;
    *(uint4*)&Bs[srow * 40 + sq * 8] = b1;
    *(uint4*)&Bs[(64 + srow) * 40 + sq * 8] = b2;
    int kn = k0 + 32;
    if (kn < K) {
      if (aok) a1 = *(const uint4*)(Ap + kn);
      b1 = *(const uint4*)(Bp1 + kn);
      b2 = *(const uint4*)(Bp2 + kn);
    }
    __syncthreads();
    short8 fa[2], fb[4];
#pragma unroll
    for (int i = 0; i < 2; i++)
      fa[i] = *(const short8*)&As[(wr * 32 + i * 16 + l16) * 40 + quad * 8];
#pragma unroll
    for (int i = 0; i < 4; i++)
      fb[i] = *(const short8*)&Bs[(wc * 64 + i * 16 + l16) * 40 + quad * 8];
#pragma unroll
    for (int mi = 0; mi < 2; mi++)
#pragma unroll
      for (int ni = 0; ni < 4; ni++)
        acc[mi][ni] = __builtin_amdgcn_mfma_f32_16x16x32_bf16(fa[mi], fb[ni], acc[mi][ni], 0, 0, 0);
  }

  float p0[2][4], p1[2][4];
#pragma unroll
  for (int mi = 0; mi < 2; mi++)
#pragma unroll
    for (int reg = 0; reg < 4; reg++) { p0[mi][reg] = 0.f; p1[mi][reg] = 0.f; }
#pragma unroll
  for (int mi = 0; mi < 2; mi++)
#pragma unroll
    for (int ni = 0; ni < 4; ni++) {
      int c = col0 + wc * 64 + ni * 16 + l16;
      float bv = bias[c];
      float w20 = w2[c * 2 + 0], w21 = w2[c * 2 + 1];
#pragma unroll
      for (int reg = 0; reg < 4; reg++) {
        float v = fmaxf(acc[mi][ni][reg] + bv, 0.f);
        p0[mi][reg] += v * w20;
        p1[mi][reg] += v * w21;
      }
    }
#pragma unroll
  for (int off = 1; off < 16; off <<= 1)
#pragma unroll
    for (int mi = 0; mi < 2; mi++)
#pragma unroll
      for (int reg = 0; reg < 4; reg++) {
        p0[mi][reg] += __shfl_xor(p0[mi][reg], off);
        p1[mi][reg] += __shfl_xor(p1[mi][reg], off);
      }
  if (l16 == 0) {
#pragma unroll
    for (int mi = 0; mi < 2; mi++)
#pragma unroll
      for (int reg = 0; reg < 4; reg++) {
        int rl = wr * 32 + mi * 16 + quad * 4 + reg;
        ls[rl][wc][0] = p0[mi][reg];
        ls[rl][wc][1] = p1[mi][reg];
      }
  }
  __syncthreads();
  if (tid < 64) {
    int r = row0 + tid;
    if (r < M) {
      atomicAdd(&out[r * 2 + 0], ls[tid][0][0] + ls[tid][1][0]);
      atomicAdd(&out[r * 2 + 1], ls[tid][0][1] + ls[tid][1][1]);
    }
  }
}

// ---------------- alpha3: apj in LDS, vectorized row loads ----------------
__global__ __launch_bounds__(256) void alpha3_k(const __hip_bfloat16* __restrict__ g2,
                                                const float* __restrict__ apj,
                                                float* __restrict__ as_, float* __restrict__ ad_,
                                                int M) {
  __shared__ float sapj[4096];
  int tid = threadIdx.x;
  for (int i = tid; i < 4096; i += 256) sapj[i] = apj[i];
  __syncthreads();
  int nl = tid >> 4, o = tid & 15;
  int n = blockIdx.x * 16 + nl;
  if (n >= M) return;
  const __hip_bfloat16* row = g2 + (size_t)n * 256;
  float s = 0.f;
  for (int cc = 0; cc < 256; cc += 8) {
    short8 v8 = *(const short8*)(row + cc);
#pragma unroll
    for (int j = 0; j < 8; j++)
      s += bf2f((unsigned short)v8[j]) * sapj[(cc + j) * 16 + o];
  }
  if (o & 1) ad_[n * 8 + (o >> 1)] = s;
  else as_[n * 8 + (o >> 1)] = s;
}

// ---------------- edge softmax (GAT3) ----------------
__global__ __launch_bounds__(256) void esoft_k(const int* __restrict__ rp,
                                               const int* __restrict__ col,
                                               const float* __restrict__ as_,
                                               const float* __restrict__ ad_,
                                               float* __restrict__ ex,
                                               float* __restrict__ invden, int M) {
  int dst = blockIdx.x * 4 + (threadIdx.x >> 6);
  if (dst >= M) return;
  int lane = threadIdx.x & 63;
  int es = lane >> 3, h = lane & 7;
  int beg = rp[dst], end = rp[dst + 1];
  float adv = ad_[dst * 8 + h];
  float m = -3.4e38f;
  for (int i = beg + es; i < end; i += 8) {
    float e = as_[col[i] * 8 + h] + adv;
    e = e > 0.f ? e : 0.2f * e;
    m = fmaxf(m, e);
  }
  m = fmaxf(m, __shfl_xor(m, 8));
  m = fmaxf(m, __shfl_xor(m, 16));
  m = fmaxf(m, __shfl_xor(m, 32));
  float den = 0.f;
  for (int i = beg + es; i < end; i += 8) {
    float e = as_[col[i] * 8 + h] + adv;
    e = e > 0.f ? e : 0.2f * e;
    float v = __expf(e - m);
    ex[(size_t)i * 8 + h] = v;
    den += v;
  }
  den += __shfl_xor(den, 8);
  den += __shfl_xor(den, 16);
  den += __shfl_xor(den, 32);
  if (es == 0) invden[dst * 8 + h] = 1.f / (den + 1e-16f);
}

// ---------------- GAT3 aggregate: 4 dsts/block, 64 thr/dst, 4-edge batches ----------------
__global__ __launch_bounds__(256) void agg3_k(const int* __restrict__ rp,
                                              const int* __restrict__ col,
                                              const __hip_bfloat16* __restrict__ g2,
                                              const float* __restrict__ ex,
                                              const float* __restrict__ invden,
                                              __hip_bfloat16* __restrict__ outA, int M) {
  int dst = blockIdx.x * 4 + (threadIdx.x >> 6);
  if (dst >= M) return;
  int t = threadIdx.x & 63;  // channels 4t..4t+3
  int beg = rp[dst], end = rp[dst + 1];
  float acc[4][8];
#pragma unroll
  for (int ch = 0; ch < 4; ch++)
#pragma unroll
    for (int h = 0; h < 8; h++) acc[ch][h] = 0.f;
  int i = beg;
  for (; i + 4 <= end; i += 4) {
    int s0 = col[i], s1 = col[i + 1], s2 = col[i + 2], s3 = col[i + 3];
    union { uint2 u; unsigned short us[4]; } u0, u1, u2, u3;
    u0.u = *(const uint2*)(g2 + (size_t)s0 * 256 + t * 4);
    u1.u = *(const uint2*)(g2 + (size_t)s1 * 256 + t * 4);
    u2.u = *(const uint2*)(g2 + (size_t)s2 * 256 + t * 4);
    u3.u = *(const uint2*)(g2 + (size_t)s3 * 256 + t * 4);
    float4 wa0 = *(const float4*)(ex + (size_t)i * 8);
    float4 wa1 = *(const float4*)(ex + (size_t)i * 8 + 4);
    float4 wb0 = *(const float4*)(ex + (size_t)(i + 1) * 8);
    float4 wb1 = *(const float4*)(ex + (size_t)(i + 1) * 8 + 4);
    float4 wc0 = *(const float4*)(ex + (size_t)(i + 2) * 8);
    float4 wc1 = *(const float4*)(ex + (size_t)(i + 2) * 8 + 4);
    float4 wd0 = *(const float4*)(ex + (size_t)(i + 3) * 8);
    float4 wd1 = *(const float4*)(ex + (size_t)(i + 3) * 8 + 4);
#pragma unroll
    for (int ch = 0; ch < 4; ch++) {
      float va = bf2f(u0.us[ch]), vb = bf2f(u1.us[ch]);
      float vc = bf2f(u2.us[ch]), vd = bf2f(u3.us[ch]);
      acc[ch][0] += wa0.x * va + wb0.x * vb + wc0.x * vc + wd0.x * vd;
      acc[ch][1] += wa0.y * va + wb0.y * vb + wc0.y * vc + wd0.y * vd;
      acc[ch][2] += wa0.z * va + wb0.z * vb + wc0.z * vc + wd0.z * vd;
      acc[ch][3] += wa0.w * va + wb0.w * vb + wc0.w * vc + wd0.w * vd;
      acc[ch][4] += wa1.x * va + wb1.x * vb + wc1.x * vc + wd1.x * vd;
      acc[ch][5] += wa1.y * va + wb1.y * vb + wc1.y * vc + wd1.y * vd;
      acc[ch][6] += wa1.z * va + wb1.z * vb + wc1.z * vc + wd1.z * vd;
      acc[ch][7] += wa1.w * va + wb1.w * vb + wc1.w * vc + wd1.w * vd;
    }
  }
  for (; i < end; i++) {
    int s = col[i];
    float4 w0 = *(const float4*)(ex + (size_t)i * 8);
    float4 w1 = *(const float4*)(ex + (size_t)i * 8 + 4);
    union { uint2 u; unsigned short us[4]; } uu;
    uu.u = *(const uint2*)(g2 + (size_t)s * 256 + t * 4);
#pragma unroll
    for (int ch = 0; ch < 4; ch++) {
      float v = bf2f(uu.us[ch]);
      acc[ch][0] += w0.x * v; acc[ch][1] += w0.y * v;
      acc[ch][2] += w0.z * v; acc[ch][3] += w0.w * v;
      acc[ch][4] += w1.x * v; acc[ch][5] += w1.y * v;
      acc[ch][6] += w1.z * v; acc[ch][7] += w1.w * v;
    }
  }
#pragma unroll
  for (int h = 0; h < 8; h++) {
    float inv = invden[dst * 8 + h];
    union { uint2 u; unsigned short us[4]; } pk;
#pragma unroll
    for (int ch = 0; ch < 4; ch++) pk.us[ch] = f2bfu(acc[ch][h] * inv);
    *(uint2*)(outA + (size_t)dst * 2048 + h * 256 + t * 4) = pk.u;
  }
}

extern "C" void kernel_launch(void* const* d_in, const int* in_sizes, int n_in,
                              void* d_out, int out_size, void* d_ws, size_t ws_size,
                              hipStream_t stream) {
  const float* x      = (const float*)d_in[0];
  const int*   ei     = (const int*)d_in[1];
  const float* w_in   = (const float*)d_in[2];
  const float* b_in   = (const float*)d_in[3];
  const float* w_t1   = (const float*)d_in[4];
  const float* b_t1   = (const float*)d_in[5];
  const float* w_t2   = (const float*)d_in[6];
  const float* b_t2   = (const float*)d_in[7];
  const float* w_g1   = (const float*)d_in[8];
  const float* a_src1 = (const float*)d_in[9];
  const float* a_dst1 = (const float*)d_in[10];
  const float* b_g1   = (const float*)d_in[11];
  const float* w_g2   = (const float*)d_in[12];
  const float* a_src2 = (const float*)d_in[13];
  const float* a_dst2 = (const float*)d_in[14];
  const float* b_g2   = (const float*)d_in[15];
  const float* w_g3   = (const float*)d_in[16];
  const float* a_src3 = (const float*)d_in[17];
  const float* a_dst3 = (const float*)d_in[18];
  const float* b_g3   = (const float*)d_in[19];
  const float* w_c1   = (const float*)d_in[20];
  const float* b_c1   = (const float*)d_in[21];
  const float* w_c2   = (const float*)d_in[22];
  const float* b_c2   = (const float*)d_in[23];
  const int M = in_sizes[0] / FIN;  // 20000
  const int E = in_sizes[1] / 2;    // 120000
  (void)n_in; (void)out_size; (void)ws_size;

  char* wsb = (char*)d_ws;
  size_t off = 0;
  auto alloc = [&](size_t bytes) {
    void* p = wsb + off;
    off = (off + bytes + 255) & ~(size_t)255;
    return p;
  };
  typedef __hip_bfloat16 bf;
  bf* xb     = (bf*)alloc((size_t)M * 256 * 2);
  bf* wtin   = (bf*)alloc(256 * 256 * 2);
  bf* wtpair = (bf*)alloc(512 * 256 * 2);
  bf* wtt2   = (bf*)alloc(256 * 256 * 2);
  bf* wtg2   = (bf*)alloc(256 * 256 * 2);
  bf* wtg3s  = (bf*)alloc(256 * 2048 * 2);
  bf* wtc1   = (bf*)alloc(256 * 512 * 2);
  bf* actA   = (bf*)alloc((size_t)M * HID * 2);      // h, later g2
  bf* actB   = (bf*)alloc((size_t)M * HID * 2);      // th, later g1
  bf* hW1    = (bf*)alloc((size_t)M * HID * 2);
  bf* comb   = (bf*)alloc((size_t)M * 2 * HID * 2);  // [g | t]
  bf* hWb    = (bf*)alloc((size_t)M * 2048 * 2);     // agg3 out
  float* as_ = (float*)alloc((size_t)M * 8 * 4);
  float* ad_ = (float*)alloc((size_t)M * 8 * 4);
  float* apj = (float*)alloc(256 * 16 * 4);
  float* exw = (float*)alloc((size_t)(E + M) * 8 * 4);
  float* ivd = (float*)alloc((size_t)M * 8 * 4);
  int* degfill = (int*)alloc((size_t)2 * M * 4);
  int* deg   = degfill;
  int* fillc = degfill + M;
  int* rp    = (int*)alloc((size_t)(M + 1) * 4);
  int* colA  = (int*)alloc((size_t)(E + M) * 4);

  // ---- prep: memset, xcvt+count+logit-init (merged), weight prep ----
  hipMemsetAsync(degfill, 0, (size_t)2 * M * 4, stream);
  int xblocks = (M * 256 + 255) / 256;
  int cblocks = (E + 255) / 256;
  int oblocks = (M * 2 + 255) / 256;
  xc_k<<<xblocks + cblocks + oblocks, 256, 0, stream>>>(x, xb, ei, deg, b_c2, (float*)d_out,
                                                        M, E, xblocks, cblocks);
  wprep_k<<<dim3(8, 16, 15), dim3(32, 8), 0, stream>>>(
      w_in, w_t1, w_g1, w_t2, w_g2, w_c1, w_g3, a_src3, a_dst3,
      wtin, wtpair, wtt2, wtg2, wtc1, wtg3s, apj);

  // ---- CSR scan ----
  scan_k<<<1, 1024, 0, stream>>>(deg, rp, M);

  int eg = (M + 3) / 4;
  int mg = (M + 63) / 64;
  int gB = 4 * mg;
  int fB = (E + M + 255) / 256;

  // fusedA: h = elu(x @ w_in + b_in) -> actA  ||  CSR fill
  fusedA_k<<<gB + fB, 256, 0, stream>>>(xb, wtin, b_in, actA, ei, rp, fillc, colA, M, E, gB);
  // dual: th=relu(h@w_t1+b_t1) -> actB ; hW1 = h@w_g1 ; alpha1 -> as_/ad_
  mgemm_dual_k<<<dim3(4, mg), 256, 0, stream>>>(actA, wtpair, b_t1, actB, hW1, M,
                                                a_src1, a_dst1, as_, ad_);
  // fusedB: t = th @ w_t2 + b_t2 -> comb[:,256:512]  ||  GAT1 aggregate -> actB'
  // NOTE: t2 GEMM reads actB (th), aggf writes g1 into... must not collide!
  // aggf output goes to a separate buffer g1buf to avoid read/write overlap.
  // (actB holds th which t2 GEMM reads concurrently.)
  {
    bf* g1buf = hW1;  // placeholder to silence unused warnings (overwritten below)
    (void)g1buf;
  }
  // Use hWb's tail region as g1 buffer (hWb not in use yet; 80MB >> 10MB needed)
  bf* g1 = hWb + (size_t)M * 1024;  // disjoint scratch within hWb
  fusedB_k<<<gB + eg, 256, 0, stream>>>(actB, wtt2, b_t2, comb + HID,
                                        rp, colA, hW1, as_, ad_, b_g1, g1, M, gB);

  // ---- GAT 2: hW2 GEMM + fused alpha2 (A = g1) ----
  mgemm64_k<0, 1><<<dim3(4, mg), 256, 0, stream>>>(g1, wtg2, nullptr, hW1, HID, M, HID, 256,
                                                   a_src2, a_dst2, as_, ad_);
  aggf_k<<<eg, 256, 0, stream>>>(rp, colA, hW1, as_, ad_, b_g2, actA, M);  // g2

  // ---- GAT 3 ----
  alpha3_k<<<(M + 15) / 16, 256, 0, stream>>>(actA, apj, as_, ad_, M);
  esoft_k<<<eg, 256, 0, stream>>>(rp, colA, as_, ad_, exw, ivd, M);
  agg3_k<<<eg, 256, 0, stream>>>(rp, colA, actA, exw, ivd, hWb, M);
  mgemm3_k<<<dim3(4, mg), 256, 0, stream>>>(hWb, wtg3s, b_g3, comb, M);

  // ---- classifier (split-N atomic logits; out pre-initialized in xc_k) ----
  mgemm_cls_k<<<dim3(2, mg), 256, 0, stream>>>(comb, wtc1, b_c1, w_c2, (float*)d_out, M);
}